// Round 12
// baseline (2148.543 us; speedup 1.0000x reference)
//
#include <hip/hip_runtime.h>

typedef unsigned short u16;
typedef unsigned int u32;
typedef float f32x4 __attribute__((ext_vector_type(4)));
typedef __bf16 bf16x8 __attribute__((ext_vector_type(8)));

static constexpr int D = 768, FFD = 3072, SIMC = 192, NH = 8, HD = 96;
static constexpr int B = 128, K = 128, M = B * K, NL = 4;
static constexpr int QKVW = 2560;   // q(768) k(768) v(768) s(192) pad(64)
static constexpr int SIMOFF = 2304;
// Q pre-scale = HD^-0.5 * log2(e)  (softmax runs in exp2 domain)
static constexpr float QSCALE = 0.14724502f;
// s pre-scale = sqrt(BOOST * log2(e))
static constexpr float SBOOST2 = 0.6578821f;
static constexpr float EPS_F = 1e-5f;

__device__ __forceinline__ float bf2f(u16 u) {
  union { u32 i; float f; } v; v.i = ((u32)u) << 16; return v.f;
}
__device__ __forceinline__ u16 f2bf(float f) {
  union { float f; u32 i; } v; v.f = f;
  u32 u = v.i;
  u32 r = (u + 0x7FFFu + ((u >> 16) & 1u)) >> 16;
  return (u16)r;
}

// tanh-form GELU via v_exp_f32/v_rcp_f32; max |err| vs erf-GELU ~3e-3.
__device__ __forceinline__ float fast_gelu(float x) {
  float u2 = x * (2.3020585f + 0.102944f * x * x);
  float e = __builtin_amdgcn_exp2f(u2);
  float r = __builtin_amdgcn_rcpf(1.0f + e);
  return x - x * r;
}

__device__ __forceinline__ void gload16(const void* g, void* l) {
  __builtin_amdgcn_global_load_lds(
      (const __attribute__((address_space(1))) void*)g,
      (__attribute__((address_space(3))) void*)l, 16, 0, 0);
}

// ---------------- add positional embedding (x is bf16 residual stream) ----------------
__global__ __launch_bounds__(256) void addpos_kernel(
    const float* __restrict__ slots, const float* __restrict__ pos,
    u16* __restrict__ x) {
  int i = blockIdx.x * 256 + threadIdx.x;
  int m = i / D;
  int d = i - m * D;
  x[i] = f2bf(slots[i] + pos[(m & (K - 1)) * D + d]);
}

// ---------------- layernorm (bf16 in; bf16 or f32 out) ----------------
__device__ __forceinline__ float block_sum(float v, float* sbuf) {
#pragma unroll
  for (int off = 32; off > 0; off >>= 1) v += __shfl_xor(v, off, 64);
  int lane = threadIdx.x & 63, w = threadIdx.x >> 6;
  if (lane == 0) sbuf[w] = v;
  __syncthreads();
  v = sbuf[0] + sbuf[1] + sbuf[2] + sbuf[3];
  __syncthreads();
  return v;
}

template <bool OUT_BF16>
__global__ __launch_bounds__(256) void ln_kernel(
    const u16* __restrict__ x, const float* __restrict__ g,
    const float* __restrict__ b, void* __restrict__ out) {
  __shared__ float sbuf[4];
  int row = blockIdx.x, tid = threadIdx.x;
  const u16* xr = x + (size_t)row * D;
  float v0 = bf2f(xr[tid]), v1 = bf2f(xr[tid + 256]), v2 = bf2f(xr[tid + 512]);
  float s = block_sum(v0 + v1 + v2, sbuf);
  float mean = s * (1.0f / D);
  float d0 = v0 - mean, d1 = v1 - mean, d2 = v2 - mean;
  float sq = block_sum(d0 * d0 + d1 * d1 + d2 * d2, sbuf);
  float rs = rsqrtf(sq * (1.0f / D) + EPS_F);
  float y0 = d0 * rs * g[tid] + b[tid];
  float y1 = d1 * rs * g[tid + 256] + b[tid + 256];
  float y2 = d2 * rs * g[tid + 512] + b[tid + 512];
  if (OUT_BF16) {
    u16* o = (u16*)out + (size_t)row * D;
    o[tid] = f2bf(y0); o[tid + 256] = f2bf(y1); o[tid + 512] = f2bf(y2);
  } else {
    float* o = (float*)out + (size_t)row * D;
    o[tid] = y0; o[tid + 256] = y1; o[tid + 512] = y2;
  }
}

// ------ ALL 4 layers' weight transposes+converts in ONE launch (hoisted) ------
struct WAll {
  const float *wq, *wk, *wv, *wo, *wsim, *wff1, *wff2;
  u16 *tA, *tB, *tC, *tD;
};
__global__ __launch_bounds__(256) void wconv_all_kernel(WAll p, float qscale) {
  __shared__ u16 t[32][33];
  int bid = blockIdx.x;
  int l = bid / 7056, b = bid - l * 7056;
  const float* W; u16* Wt; int N, Kd, n0, k0;
  float sc = 1.0f;
  if (b < 2304) {
    int z = b / 576, rem = b - z * 576;
    N = 768; Kd = 768;
    n0 = (rem % 24) * 32; k0 = (rem / 24) * 32;
    if (z == 0) { W = p.wq + (size_t)l * 589824; Wt = p.tA + (size_t)l * 1966080; sc = qscale; }
    else if (z == 1) { W = p.wk + (size_t)l * 589824; Wt = p.tA + (size_t)l * 1966080 + 589824; }
    else if (z == 2) { W = p.wv + (size_t)l * 589824; Wt = p.tA + (size_t)l * 1966080 + 1179648; }
    else { W = p.wo + (size_t)l * 589824; Wt = p.tB + (size_t)l * 589824; }
  } else if (b < 2448) {
    int rem = b - 2304;
    W = p.wsim + (size_t)l * 147456;
    Wt = p.tA + (size_t)l * 1966080 + (size_t)SIMOFF * 768;
    N = SIMC; Kd = 768;
    n0 = (rem % 6) * 32; k0 = (rem / 6) * 32;
  } else if (b < 4752) {
    int rem = b - 2448;
    W = p.wff1 + (size_t)l * 2359296; Wt = p.tC + (size_t)l * 2359296;
    N = FFD; Kd = 768;
    n0 = (rem % 96) * 32; k0 = (rem / 96) * 32;
  } else {
    int rem = b - 4752;
    W = p.wff2 + (size_t)l * 2359296; Wt = p.tD + (size_t)l * 2359296;
    N = 768; Kd = FFD;
    n0 = (rem % 24) * 32; k0 = (rem / 24) * 32;
  }
  int tid = threadIdx.x;
  int c = tid & 31, r4 = tid >> 5;
#pragma unroll
  for (int i = 0; i < 4; ++i) {
    int r = r4 + i * 8;
    t[r][c] = f2bf(W[(size_t)(k0 + r) * N + n0 + c] * sc);
  }
  __syncthreads();
#pragma unroll
  for (int i = 0; i < 4; ++i) {
    int r = r4 + i * 8;
    Wt[(size_t)(n0 + r) * Kd + k0 + c] = t[c][r];
  }
}

// ===================== 256x256 GEMM, B direct from global (L1/L2), A via LDS ==========
// C[M,N] = A[M,K](bf16) @ Bt[N,K]^T(bf16).  512 thr = 8 waves (2M x 4N), BK=64.
// A double-buffered in LDS (64KB, XOR-swizzled as verified r7); B fragments are
// loaded straight global->VGPR each K-tile (one dwordx4 per frag; wm-pair waves
// read identical addresses -> L1 broadcast; panels are L2-resident).
// ONE barrier per K-tile: { B loads(8) ; SB ; stageA(t+1) ; readA0 ; MFMA(0,*) ;
//   readA1 ; MFMA(1,*) ; vmcnt(0)+lgkmcnt(0) ; barrier }.
// Ledger: stage targets buf[cur^1], whose reads completed before the PREVIOUS
// barrier (lgkmcnt(0) precedes every barrier); end-of-phase vmcnt(0) guarantees
// buf[cur^1] is fully written before the next tile reads it. B is register-only
// (compiler inserts exact vmcnt for br deps; B issued first so that wait leaves
// the 4 stage loads in flight). Last tile stages nothing.
template <bool BIAS, bool GELU_, bool RESID>
__global__ __launch_bounds__(512, 2) void gemm256_kernel(
    const u16* __restrict__ A, const u16* __restrict__ Bt,
    const float* __restrict__ bias, const u16* __restrict__ resid,
    u16* __restrict__ Cout, int N, int Kdim, int NBX) {
  __shared__ u16 lds[32768];  // A dbuf: 2 x 256x64
  int tid = threadIdx.x;
  int w = tid >> 6, lane = tid & 63;
  int wm = w >> 2, wn = w & 3;
  int lr = lane & 15, lg = lane >> 4;

  int nwg = gridDim.x;
  int cpx = nwg >> 3;
  int swz = (blockIdx.x & 7) * cpx + (blockIdx.x >> 3);
  int bx = swz % NBX, by = swz / NBX;
  int n0 = bx << 8, m0 = by << 8;

  int scol = ((lane & 7) ^ (lane >> 3)) << 3;
  size_t aOff = (size_t)((w << 4) + (lane >> 3)) * Kdim + scol;
  u16* ldsU = lds;

  auto stageA = [&](int buf, int h, int t) {
    const u16* g = A + (size_t)(m0 + (h << 7)) * Kdim + ((size_t)t << 6) + aOff;
    u16* l = ldsU + buf * 16384 + h * 8192 + (w << 10);
    gload16(g, l);
    gload16(g + ((size_t)Kdim << 3), l + 512);
  };

  // B row base pointers (4 frag rows per wave), advanced by immediate offsets
  const u16* Brow[4];
#pragma unroll
  for (int j = 0; j < 4; ++j) {
    int nseg = j >> 1, nn = j & 1;
    Brow[j] = Bt + (size_t)(n0 + wn * 64 + nseg * 32 + nn * 16 + lr) * Kdim + lg * 8;
  }

  int arow = (wm * 128 + lr) * 64;
  int swz0 = (((lg * 16)) ^ ((lr & 7) << 4)) >> 1;
  int swz1 = ((64 + lg * 16) ^ ((lr & 7) << 4)) >> 1;

  f32x4 acc[8][4] = {};
  bf16x8 ar[2][4], br[2][4];

#define READ_A_KS(BASE, MSEG, KS)                                            \
  do {                                                                       \
    _Pragma("unroll") for (int mm = 0; mm < 4; ++mm) {                       \
      const u16* p_ = (BASE) + arow + ((MSEG) * 64 + mm * 16) * 64;          \
      ar[KS][mm] = *(const bf16x8*)(p_ + ((KS) ? swz1 : swz0));              \
    }                                                                        \
  } while (0)
#define MFMA_Q(MSEG, NSEG)                                                   \
  do {                                                                       \
    __builtin_amdgcn_s_setprio(1);                                           \
    _Pragma("unroll") for (int ks = 0; ks < 2; ++ks)                         \
      _Pragma("unroll") for (int mm = 0; mm < 4; ++mm)                       \
        _Pragma("unroll") for (int nn = 0; nn < 2; ++nn)                     \
          acc[(MSEG) * 4 + mm][(NSEG) * 2 + nn] =                            \
              __builtin_amdgcn_mfma_f32_16x16x32_bf16(                       \
                  ar[ks][mm], br[ks][(NSEG) * 2 + nn],                       \
                  acc[(MSEG) * 4 + mm][(NSEG) * 2 + nn], 0, 0, 0);           \
    __builtin_amdgcn_s_setprio(0);                                           \
  } while (0)
#define PSYNC_END()                                                          \
  do {                                                                       \
    __builtin_amdgcn_sched_barrier(0);                                       \
    asm volatile("s_waitcnt vmcnt(0) lgkmcnt(0)" ::: "memory");              \
    __builtin_amdgcn_s_barrier();                                            \
    __builtin_amdgcn_sched_barrier(0);                                       \
  } while (0)

  int NK = Kdim >> 6;
  // prologue: tile0 A -> buf0
  stageA(0, 0, 0); stageA(0, 1, 0);
  asm volatile("s_waitcnt vmcnt(0)" ::: "memory");
  __builtin_amdgcn_s_barrier();
  __builtin_amdgcn_sched_barrier(0);

  for (int t = 0; t < NK; ++t) {
    int cur = t & 1;
    const u16* lA = ldsU + cur * 16384;
    // B fragment loads first (register destination; compiler tracks vmcnt)
#pragma unroll
    for (int ks = 0; ks < 2; ++ks)
#pragma unroll
      for (int j = 0; j < 4; ++j)
        br[ks][j] = *(const bf16x8*)(Brow[j] + t * 64 + ks * 32);
    __builtin_amdgcn_sched_barrier(0);  // keep B loads issued first
    if (t + 1 < NK) { stageA(cur ^ 1, 0, t + 1); stageA(cur ^ 1, 1, t + 1); }
    READ_A_KS(lA, 0, 0); READ_A_KS(lA, 0, 1);
    MFMA_Q(0, 0); MFMA_Q(0, 1);
    READ_A_KS(lA, 1, 0); READ_A_KS(lA, 1, 1);
    MFMA_Q(1, 0); MFMA_Q(1, 1);
    PSYNC_END();
  }

  // ---- epilogue ----
#pragma unroll
  for (int m = 0; m < 8; ++m) {
#pragma unroll
    for (int n = 0; n < 4; ++n) {
      int col = n0 + wn * 64 + n * 16 + lr;
      float bv = BIAS ? bias[col] : 0.0f;
#pragma unroll
      for (int r = 0; r < 4; ++r) {
        int row = m0 + wm * 128 + m * 16 + lg * 4 + r;
        float v = acc[m][n][r];
        if (BIAS) v += bv;
        if (GELU_) v = fast_gelu(v);
        if (RESID) v += bf2f(resid[(size_t)row * N + col]);
        Cout[(size_t)row * N + col] = f2bf(v);
      }
    }
  }
#undef READ_A_KS
#undef MFMA_Q
#undef PSYNC_END
}

// --------- per-batch sim precompute: psim[b] = (norm(s_b)*SBOOST2)(...)^T ---------
__global__ __launch_bounds__(256) void simpre_kernel(
    const u16* __restrict__ qkvb, u16* __restrict__ psim) {
  __shared__ u16 sln[128][200];
  int b = blockIdx.x, tid = threadIdx.x;
  {
    int row = tid >> 1, half = tid & 1;
    const u16* sr = qkvb + ((size_t)(b * K + row)) * QKVW + SIMOFF + half * 96;
    u16 v[96];
    float sq = 0.f;
#pragma unroll
    for (int j = 0; j < 12; ++j) {
      uint4 u4 = *(const uint4*)(sr + j * 8);
      u32 uu[4] = {u4.x, u4.y, u4.z, u4.w};
#pragma unroll
      for (int t = 0; t < 4; ++t) {
        v[j * 8 + 2 * t] = (u16)(uu[t] & 0xffffu);
        v[j * 8 + 2 * t + 1] = (u16)(uu[t] >> 16);
      }
    }
#pragma unroll
    for (int j = 0; j < 96; ++j) { float f = bf2f(v[j]); sq += f * f; }
    sq += __shfl_xor(sq, 1, 64);
    float inv = SBOOST2 / fmaxf(sqrtf(sq), 1e-12f);
#pragma unroll
    for (int j = 0; j < 96; ++j) sln[row][half * 96 + j] = f2bf(bf2f(v[j]) * inv);
  }
  __syncthreads();
  int w = tid >> 6, lane = tid & 63;
  int lr = lane & 15, lg = lane >> 4;
  int q0 = 32 * w;
  f32x4 accs[2][8] = {};
#pragma unroll
  for (int ks = 0; ks < 6; ++ks) {
    bf16x8 af[2];
#pragma unroll
    for (int m = 0; m < 2; ++m)
      af[m] = *(const bf16x8*)(&sln[q0 + 16 * m + lr][ks * 32 + lg * 8]);
#pragma unroll
    for (int n = 0; n < 8; ++n) {
      bf16x8 bf = *(const bf16x8*)(&sln[16 * n + lr][ks * 32 + lg * 8]);
#pragma unroll
      for (int m = 0; m < 2; ++m)
        accs[m][n] = __builtin_amdgcn_mfma_f32_16x16x32_bf16(af[m], bf, accs[m][n], 0, 0, 0);
    }
  }
  u16* pb = psim + (size_t)b * K * K;
#pragma unroll
  for (int m = 0; m < 2; ++m)
#pragma unroll
    for (int n = 0; n < 8; ++n)
#pragma unroll
      for (int r = 0; r < 4; ++r)
        pb[(size_t)(q0 + 16 * m + 4 * lg + r) * K + 16 * n + lr] = f2bf(accs[m][n][r]);
}

// ---------------- MFMA attention: one block per (b,h), 4 waves x 32 q-rows ----------------
__global__ __launch_bounds__(256) void attn_kernel(
    const u16* __restrict__ qkv, const u16* __restrict__ psim,
    u16* __restrict__ ob) {
  __shared__ u16 Vt[96][136];
  __shared__ u16 Pl[4][32][136];
  int bh = blockIdx.x, b = bh >> 3, h = bh & 7;
  int tid = threadIdx.x, w = tid >> 6, lane = tid & 63;
  int lr = lane & 15, lg = lane >> 4;
  const u16* qb = qkv + (size_t)b * K * QKVW + h * HD;
  const u16* kb = qb + D;
  const u16* vb = qb + 2 * D;
  for (int idx = tid; idx < 128 * 12; idx += 256) {
    int r = idx / 12, db = idx - r * 12;
    uint4 v4 = *(const uint4*)(vb + (size_t)r * QKVW + db * 8);
    u32 vv[4] = {v4.x, v4.y, v4.z, v4.w};
#pragma unroll
    for (int j = 0; j < 4; ++j) {
      Vt[db * 8 + 2 * j][r] = (u16)(vv[j] & 0xffffu);
      Vt[db * 8 + 2 * j + 1][r] = (u16)(vv[j] >> 16);
    }
  }
  u16* siml = &Pl[0][0][0];
  {
    const u16* pb = psim + (size_t)b * K * K;
    for (int c = tid; c < 2048; c += 256) {
      int r = c >> 4, cc = c & 15;
      *(uint4*)(siml + r * 136 + cc * 8) = *(const uint4*)(pb + r * 128 + cc * 8);
    }
  }
  __syncthreads();
  int q0 = 32 * w;
  f32x4 accs[2][8];
#pragma unroll
  for (int m = 0; m < 2; ++m)
#pragma unroll
    for (int n = 0; n < 8; ++n)
#pragma unroll
      for (int r = 0; r < 4; ++r)
        accs[m][n][r] = bf2f(siml[(q0 + 16 * m + 4 * lg + r) * 136 + 16 * n + lr]);
#pragma unroll
  for (int ks = 0; ks < 3; ++ks) {
    bf16x8 af[2];
#pragma unroll
    for (int m = 0; m < 2; ++m)
      af[m] = *(const bf16x8*)(qb + (size_t)(q0 + 16 * m + lr) * QKVW + ks * 32 + lg * 8);
#pragma unroll
    for (int n = 0; n < 8; ++n) {
      bf16x8 bf = *(const bf16x8*)(kb + (size_t)(16 * n + lr) * QKVW + ks * 32 + lg * 8);
#pragma unroll
      for (int m = 0; m < 2; ++m)
        accs[m][n] = __builtin_amdgcn_mfma_f32_16x16x32_bf16(af[m], bf, accs[m][n], 0, 0, 0);
    }
  }
#pragma unroll
  for (int m = 0; m < 2; ++m) {
    float mx[4] = {-3e38f, -3e38f, -3e38f, -3e38f};
#pragma unroll
    for (int n = 0; n < 8; ++n)
#pragma unroll
      for (int r = 0; r < 4; ++r) mx[r] = fmaxf(mx[r], accs[m][n][r]);
#pragma unroll
    for (int r = 0; r < 4; ++r) {
      mx[r] = fmaxf(mx[r], __shfl_xor(mx[r], 1, 64));
      mx[r] = fmaxf(mx[r], __shfl_xor(mx[r], 2, 64));
      mx[r] = fmaxf(mx[r], __shfl_xor(mx[r], 4, 64));
      mx[r] = fmaxf(mx[r], __shfl_xor(mx[r], 8, 64));
    }
    float sm[4] = {0.f, 0.f, 0.f, 0.f};
#pragma unroll
    for (int n = 0; n < 8; ++n)
#pragma unroll
      for (int r = 0; r < 4; ++r) {
        float e = __builtin_amdgcn_exp2f(accs[m][n][r] - mx[r]);
        accs[m][n][r] = e;
        sm[r] += e;
      }
#pragma unroll
    for (int r = 0; r < 4; ++r) {
      sm[r] += __shfl_xor(sm[r], 1, 64);
      sm[r] += __shfl_xor(sm[r], 2, 64);
      sm[r] += __shfl_xor(sm[r], 4, 64);
      sm[r] += __shfl_xor(sm[r], 8, 64);
    }
    float inv[4];
#pragma unroll
    for (int r = 0; r < 4; ++r) inv[r] = 1.0f / sm[r];
#pragma unroll
    for (int n = 0; n < 8; ++n)
#pragma unroll
      for (int r = 0; r < 4; ++r)
        Pl[w][16 * m + 4 * lg + r][16 * n + lr] = f2bf(accs[m][n][r] * inv[r]);
  }
  __syncthreads();
  f32x4 acco[2][6] = {};
#pragma unroll
  for (int ks = 0; ks < 4; ++ks) {
    bf16x8 pa[2];
#pragma unroll
    for (int m = 0; m < 2; ++m)
      pa[m] = *(const bf16x8*)(&Pl[w][16 * m + lr][ks * 32 + lg * 8]);
#pragma unroll
    for (int n = 0; n < 6; ++n) {
      bf16x8 bv = *(const bf16x8*)(&Vt[16 * n + lr][ks * 32 + lg * 8]);
#pragma unroll
      for (int m = 0; m < 2; ++m)
        acco[m][n] = __builtin_amdgcn_mfma_f32_16x16x32_bf16(pa[m], bv, acco[m][n], 0, 0, 0);
    }
  }
  u16* obb = ob + (size_t)b * K * D + h * HD;
#pragma unroll
  for (int m = 0; m < 2; ++m)
#pragma unroll
    for (int n = 0; n < 6; ++n)
#pragma unroll
      for (int r = 0; r < 4; ++r)
        obb[(size_t)(q0 + 16 * m + 4 * lg + r) * D + 16 * n + lr] = f2bf(acco[m][n][r]);
}

// ---------------- host ----------------
extern "C" void kernel_launch(void* const* d_in, const int* in_sizes, int n_in,
                              void* d_out, int out_size, void* d_ws, size_t ws_size,
                              hipStream_t stream) {
  (void)in_sizes; (void)n_in; (void)out_size;
  const float* slots = (const float*)d_in[0];
  const float* pos   = (const float*)d_in[1];
  const float* Wq    = (const float*)d_in[2];
  const float* Wk    = (const float*)d_in[3];
  const float* Wv    = (const float*)d_in[4];
  const float* Wo    = (const float*)d_in[5];
  const float* bo    = (const float*)d_in[6];
  const float* Wsim  = (const float*)d_in[7];
  const float* g1    = (const float*)d_in[8];
  const float* b1    = (const float*)d_in[9];
  const float* g2    = (const float*)d_in[10];
  const float* b2    = (const float*)d_in[11];
  const float* Wff1  = (const float*)d_in[12];
  const float* bff1  = (const float*)d_in[13];
  const float* Wff2  = (const float*)d_in[14];
  const float* bff2  = (const float*)d_in[15];
  const float* gf    = (const float*)d_in[16];
  const float* bfin  = (const float*)d_in[17];

  char* p = (char*)d_ws;
  u16*   x    = (u16*)p;   p += (size_t)M * D * 2;          // 25.2 MB
  u16*   nx   = (u16*)p;   p += (size_t)M * D * 2;          // 25.2 MB
  u16*   qkvb = (u16*)p;   p += (size_t)M * QKVW * 2;       // 83.9 MB
  u16*   ob   = (u16*)p;   p += (size_t)M * D * 2;          // 25.2 MB
  u16*   psim = (u16*)p;   p += (size_t)B * K * K * 2;      // 4.2 MB
  u16*   wtA4 = (u16*)p;   p += (size_t)4 * QKVW * D * 2;   // 15.7 MB
  u16*   wtB4 = (u16*)p;   p += (size_t)4 * D * D * 2;      // 4.7 MB
  u16*   wtC4 = (u16*)p;   p += (size_t)4 * FFD * D * 2;    // 18.9 MB
  u16*   wtD4 = (u16*)p;   p += (size_t)4 * D * FFD * 2;    // 18.9 MB
  if ((size_t)(p - (char*)d_ws) > ws_size) return;          // 221.8 MB <= proven 222.3
  u16* hb = qkvb;  // [M][3072] ffn hidden (spans qkvb+ob = 109 MB >= 100.7 MB)

  addpos_kernel<<<M * D / 256, 256, 0, stream>>>(slots, pos, x);
  WAll wp = {Wq, Wk, Wv, Wo, Wsim, Wff1, Wff2, wtA4, wtB4, wtC4, wtD4};
  wconv_all_kernel<<<28224, 256, 0, stream>>>(wp, QSCALE);

  int nbx_qkv = QKVW / 256, nwg_qkv = nbx_qkv * (M / 256);  // 10 x 64 = 640
  int nbx_o   = D / 256,    nwg_o   = nbx_o * (M / 256);    // 3 x 64 = 192
  int nbx_f1  = FFD / 256,  nwg_f1  = nbx_f1 * (M / 256);   // 12 x 64 = 768

  for (int l = 0; l < NL; ++l) {
    ln_kernel<true><<<M, 256, 0, stream>>>(x, g1 + l * D, b1 + l * D, nx);
    gemm256_kernel<false, false, false><<<nwg_qkv, 512, 0, stream>>>(
        nx, wtA4 + (size_t)l * QKVW * D, nullptr, nullptr, qkvb, QKVW, D, nbx_qkv);
    simpre_kernel<<<B, 256, 0, stream>>>(qkvb, psim);
    attn_kernel<<<B * NH, 256, 0, stream>>>(qkvb, psim, ob);
    gemm256_kernel<true, false, true><<<nwg_o, 512, 0, stream>>>(
        ob, wtB4 + (size_t)l * D * D, bo + l * D, x, x, D, D, nbx_o);
    ln_kernel<true><<<M, 256, 0, stream>>>(x, g2 + l * D, b2 + l * D, nx);
    gemm256_kernel<true, true, false><<<nwg_f1, 512, 0, stream>>>(
        nx, wtC4 + (size_t)l * FFD * D, bff1 + l * FFD, nullptr, hb, FFD, D, nbx_f1);
    gemm256_kernel<true, false, true><<<nwg_o, 512, 0, stream>>>(
        hb, wtD4 + (size_t)l * D * FFD, bff2 + l * D, x, x, D, FFD, nbx_o);
  }
  ln_kernel<false><<<M, 256, 0, stream>>>(x, gf, bfin, d_out);
}

// Round 13
// 1436.972 us; speedup vs baseline: 1.4952x; 1.4952x over previous
//
#include <hip/hip_runtime.h>

typedef unsigned short u16;
typedef unsigned int u32;
typedef float f32x4 __attribute__((ext_vector_type(4)));
typedef __bf16 bf16x8 __attribute__((ext_vector_type(8)));

static constexpr int D = 768, FFD = 3072, SIMC = 192, NH = 8, HD = 96;
static constexpr int B = 128, K = 128, M = B * K, NL = 4;
static constexpr int QKVW = 2560;   // q(768) k(768) v(768) s(192) pad(64)
static constexpr int SIMOFF = 2304;
// Q pre-scale = HD^-0.5 * log2(e)  (softmax runs in exp2 domain)
static constexpr float QSCALE = 0.14724502f;
// s pre-scale = sqrt(BOOST * log2(e))
static constexpr float SBOOST2 = 0.6578821f;
static constexpr float EPS_F = 1e-5f;

__device__ __forceinline__ float bf2f(u16 u) {
  union { u32 i; float f; } v; v.i = ((u32)u) << 16; return v.f;
}
__device__ __forceinline__ u16 f2bf(float f) {
  union { float f; u32 i; } v; v.f = f;
  u32 u = v.i;
  u32 r = (u + 0x7FFFu + ((u >> 16) & 1u)) >> 16;
  return (u16)r;
}

// tanh-form GELU via v_exp_f32/v_rcp_f32; max |err| vs erf-GELU ~3e-3.
__device__ __forceinline__ float fast_gelu(float x) {
  float u2 = x * (2.3020585f + 0.102944f * x * x);
  float e = __builtin_amdgcn_exp2f(u2);
  float r = __builtin_amdgcn_rcpf(1.0f + e);
  return x - x * r;
}

__device__ __forceinline__ void gload16(const void* g, void* l) {
  __builtin_amdgcn_global_load_lds(
      (const __attribute__((address_space(1))) void*)g,
      (__attribute__((address_space(3))) void*)l, 16, 0, 0);
}

// ---------------- add positional embedding (x is bf16 residual stream) ----------------
__global__ __launch_bounds__(256) void addpos_kernel(
    const float* __restrict__ slots, const float* __restrict__ pos,
    u16* __restrict__ x) {
  int i = blockIdx.x * 256 + threadIdx.x;
  int m = i / D;
  int d = i - m * D;
  x[i] = f2bf(slots[i] + pos[(m & (K - 1)) * D + d]);
}

// ---------------- layernorm (bf16 in; bf16 or f32 out) ----------------
__device__ __forceinline__ float block_sum(float v, float* sbuf) {
#pragma unroll
  for (int off = 32; off > 0; off >>= 1) v += __shfl_xor(v, off, 64);
  int lane = threadIdx.x & 63, w = threadIdx.x >> 6;
  if (lane == 0) sbuf[w] = v;
  __syncthreads();
  v = sbuf[0] + sbuf[1] + sbuf[2] + sbuf[3];
  __syncthreads();
  return v;
}

template <bool OUT_BF16>
__global__ __launch_bounds__(256) void ln_kernel(
    const u16* __restrict__ x, const float* __restrict__ g,
    const float* __restrict__ b, void* __restrict__ out) {
  __shared__ float sbuf[4];
  int row = blockIdx.x, tid = threadIdx.x;
  const u16* xr = x + (size_t)row * D;
  float v0 = bf2f(xr[tid]), v1 = bf2f(xr[tid + 256]), v2 = bf2f(xr[tid + 512]);
  float s = block_sum(v0 + v1 + v2, sbuf);
  float mean = s * (1.0f / D);
  float d0 = v0 - mean, d1 = v1 - mean, d2 = v2 - mean;
  float sq = block_sum(d0 * d0 + d1 * d1 + d2 * d2, sbuf);
  float rs = rsqrtf(sq * (1.0f / D) + EPS_F);
  float y0 = d0 * rs * g[tid] + b[tid];
  float y1 = d1 * rs * g[tid + 256] + b[tid + 256];
  float y2 = d2 * rs * g[tid + 512] + b[tid + 512];
  if (OUT_BF16) {
    u16* o = (u16*)out + (size_t)row * D;
    o[tid] = f2bf(y0); o[tid + 256] = f2bf(y1); o[tid + 512] = f2bf(y2);
  } else {
    float* o = (float*)out + (size_t)row * D;
    o[tid] = y0; o[tid + 256] = y1; o[tid + 512] = y2;
  }
}

// ------ ALL 4 layers' weight transposes+converts in ONE launch (hoisted) ------
struct WAll {
  const float *wq, *wk, *wv, *wo, *wsim, *wff1, *wff2;
  u16 *tA, *tB, *tC, *tD;
};
__global__ __launch_bounds__(256) void wconv_all_kernel(WAll p, float qscale) {
  __shared__ u16 t[32][33];
  int bid = blockIdx.x;
  int l = bid / 7056, b = bid - l * 7056;
  const float* W; u16* Wt; int N, Kd, n0, k0;
  float sc = 1.0f;
  if (b < 2304) {
    int z = b / 576, rem = b - z * 576;
    N = 768; Kd = 768;
    n0 = (rem % 24) * 32; k0 = (rem / 24) * 32;
    if (z == 0) { W = p.wq + (size_t)l * 589824; Wt = p.tA + (size_t)l * 1966080; sc = qscale; }
    else if (z == 1) { W = p.wk + (size_t)l * 589824; Wt = p.tA + (size_t)l * 1966080 + 589824; }
    else if (z == 2) { W = p.wv + (size_t)l * 589824; Wt = p.tA + (size_t)l * 1966080 + 1179648; }
    else { W = p.wo + (size_t)l * 589824; Wt = p.tB + (size_t)l * 589824; }
  } else if (b < 2448) {
    int rem = b - 2304;
    W = p.wsim + (size_t)l * 147456;
    Wt = p.tA + (size_t)l * 1966080 + (size_t)SIMOFF * 768;
    N = SIMC; Kd = 768;
    n0 = (rem % 6) * 32; k0 = (rem / 6) * 32;
  } else if (b < 4752) {
    int rem = b - 2448;
    W = p.wff1 + (size_t)l * 2359296; Wt = p.tC + (size_t)l * 2359296;
    N = FFD; Kd = 768;
    n0 = (rem % 96) * 32; k0 = (rem / 96) * 32;
  } else {
    int rem = b - 4752;
    W = p.wff2 + (size_t)l * 2359296; Wt = p.tD + (size_t)l * 2359296;
    N = 768; Kd = FFD;
    n0 = (rem % 24) * 32; k0 = (rem / 24) * 32;
  }
  int tid = threadIdx.x;
  int c = tid & 31, r4 = tid >> 5;
#pragma unroll
  for (int i = 0; i < 4; ++i) {
    int r = r4 + i * 8;
    t[r][c] = f2bf(W[(size_t)(k0 + r) * N + n0 + c] * sc);
  }
  __syncthreads();
#pragma unroll
  for (int i = 0; i < 4; ++i) {
    int r = r4 + i * 8;
    Wt[(size_t)(n0 + r) * Kd + k0 + c] = t[c][r];
  }
}

// ===================== 256x256 4-phase GEMM (verified r11) =====================
// See r11 comments: ledger verified; B in LDS; XOR swizzle per rule 21.
template <bool BIAS, bool GELU_, bool RESID>
__global__ __launch_bounds__(512, 2) void gemm256_kernel(
    const u16* __restrict__ A, const u16* __restrict__ Bt,
    const float* __restrict__ bias, const u16* __restrict__ resid,
    u16* __restrict__ Cout, int N, int Kdim, int NBX) {
  __shared__ u16 lds[65536];
  int tid = threadIdx.x;
  int w = tid >> 6, lane = tid & 63;
  int wm = w >> 2, wn = w & 3;
  int lr = lane & 15, lg = lane >> 4;

  int nwg = gridDim.x;
  int cpx = nwg >> 3;
  int swz = (blockIdx.x & 7) * cpx + (blockIdx.x >> 3);
  int bx = swz % NBX, by = swz / NBX;
  int n0 = bx << 8, m0 = by << 8;

  int scol = ((lane & 7) ^ (lane >> 3)) << 3;
  size_t aOff = (size_t)((w << 4) + (lane >> 3)) * Kdim + scol;
  u16* ldsU = lds;

  auto stageA = [&](int buf, int h, int t) {
    const u16* g = A + (size_t)(m0 + (h << 7)) * Kdim + ((size_t)t << 6) + aOff;
    u16* l = ldsU + buf * 32768 + h * 8192 + (w << 10);
    gload16(g, l);
    gload16(g + ((size_t)Kdim << 3), l + 512);
  };
  auto stageB = [&](int buf, int h, int t) {
    const u16* g = Bt + (size_t)(n0 + (h << 7)) * Kdim + ((size_t)t << 6) + aOff;
    u16* l = ldsU + buf * 32768 + 16384 + h * 8192 + (w << 10);
    gload16(g, l);
    gload16(g + ((size_t)Kdim << 3), l + 512);
  };

  const u16* lA0p = ldsU;
  const u16* lB0p = ldsU + 16384;
  const u16* lA1p = ldsU + 32768;
  const u16* lB1p = ldsU + 49152;
  int arow = (wm * 128 + lr) * 64;
  int brow = (wn * 64 + lr) * 64;
  int swz0 = (((lg * 16)) ^ ((lr & 7) << 4)) >> 1;
  int swz1 = ((64 + lg * 16) ^ ((lr & 7) << 4)) >> 1;

  f32x4 acc[8][4] = {};
  bf16x8 ar[2][4], br[2][4];

#define READ_A_KS(BASE, MSEG, KS)                                            \
  do {                                                                       \
    _Pragma("unroll") for (int mm = 0; mm < 4; ++mm) {                       \
      const u16* p_ = (BASE) + arow + ((MSEG) * 64 + mm * 16) * 64;          \
      ar[KS][mm] = *(const bf16x8*)(p_ + ((KS) ? swz1 : swz0));              \
    }                                                                        \
  } while (0)
#define READ_B_KS(BASE, NSEG, KS)                                            \
  do {                                                                       \
    _Pragma("unroll") for (int nn = 0; nn < 2; ++nn) {                       \
      const u16* p_ = (BASE) + brow + ((NSEG) * 32 + nn * 16) * 64;          \
      br[KS][(NSEG) * 2 + nn] = *(const bf16x8*)(p_ + ((KS) ? swz1 : swz0)); \
    }                                                                        \
  } while (0)
#define MFMA_Q(MSEG, NSEG)                                                   \
  do {                                                                       \
    __builtin_amdgcn_s_setprio(1);                                           \
    _Pragma("unroll") for (int ks = 0; ks < 2; ++ks)                         \
      _Pragma("unroll") for (int mm = 0; mm < 4; ++mm)                       \
        _Pragma("unroll") for (int nn = 0; nn < 2; ++nn)                     \
          acc[(MSEG) * 4 + mm][(NSEG) * 2 + nn] =                            \
              __builtin_amdgcn_mfma_f32_16x16x32_bf16(                       \
                  ar[ks][mm], br[ks][(NSEG) * 2 + nn],                       \
                  acc[(MSEG) * 4 + mm][(NSEG) * 2 + nn], 0, 0, 0);           \
    __builtin_amdgcn_s_setprio(0);                                           \
  } while (0)
#define PSYNC()                                                              \
  do {                                                                       \
    __builtin_amdgcn_sched_barrier(0);                                       \
    asm volatile("s_waitcnt lgkmcnt(0)" ::: "memory");                       \
    __builtin_amdgcn_s_barrier();                                            \
    __builtin_amdgcn_sched_barrier(0);                                       \
  } while (0)
#define PSYNC_V(N)                                                           \
  do {                                                                       \
    __builtin_amdgcn_sched_barrier(0);                                       \
    asm volatile("s_waitcnt vmcnt(" #N ") lgkmcnt(0)" ::: "memory");         \
    __builtin_amdgcn_s_barrier();                                            \
    __builtin_amdgcn_sched_barrier(0);                                       \
  } while (0)

  int NK = Kdim >> 6, NI = NK >> 1;
  // prologue: tile0 -> buf0 (A+B), tile1 B -> buf1
  stageA(0, 0, 0); stageA(0, 1, 0); stageB(0, 0, 0); stageB(0, 1, 0);
  stageB(1, 0, 1); stageB(1, 1, 1);
  asm volatile("s_waitcnt vmcnt(4)" ::: "memory");
  __builtin_amdgcn_s_barrier();
  __builtin_amdgcn_sched_barrier(0);

  for (int i = 0; i < NI; ++i) {
    int t1 = 2 * i + 1, t2 = 2 * i + 2, t3 = 2 * i + 3;
    bool last = (i == NI - 1);
    // ---- P1 ----
    stageA(1, 0, t1); stageA(1, 1, t1);
    READ_A_KS(lA0p, 0, 0); READ_B_KS(lB0p, 0, 0); READ_B_KS(lB0p, 1, 0);
    READ_A_KS(lA0p, 0, 1); READ_B_KS(lB0p, 0, 1); READ_B_KS(lB0p, 1, 1);
    MFMA_Q(0, 0); MFMA_Q(0, 1);
    PSYNC();
    // ---- P2 ----
    if (!last) { stageB(0, 0, t2); stageB(0, 1, t2); }
    READ_A_KS(lA0p, 1, 0); READ_A_KS(lA0p, 1, 1);
    MFMA_Q(1, 0); MFMA_Q(1, 1);
    if (last) PSYNC_V(0);
    else      PSYNC_V(4);
    // ---- P3 ----
    if (!last) { stageA(0, 0, t2); stageA(0, 1, t2); }
    READ_A_KS(lA1p, 0, 0); READ_B_KS(lB1p, 0, 0); READ_B_KS(lB1p, 1, 0);
    READ_A_KS(lA1p, 0, 1); READ_B_KS(lB1p, 0, 1); READ_B_KS(lB1p, 1, 1);
    MFMA_Q(0, 0); MFMA_Q(0, 1);
    PSYNC();
    // ---- P4 ----
    if (!last) { stageB(1, 0, t3); stageB(1, 1, t3); }
    READ_A_KS(lA1p, 1, 0); READ_A_KS(lA1p, 1, 1);
    MFMA_Q(1, 0); MFMA_Q(1, 1);
    if (last) PSYNC();
    else      PSYNC_V(4);
  }

  // ---- epilogue ----
#pragma unroll
  for (int m = 0; m < 8; ++m) {
#pragma unroll
    for (int n = 0; n < 4; ++n) {
      int col = n0 + wn * 64 + n * 16 + lr;
      float bv = BIAS ? bias[col] : 0.0f;
#pragma unroll
      for (int r = 0; r < 4; ++r) {
        int row = m0 + wm * 128 + m * 16 + lg * 4 + r;
        float v = acc[m][n][r];
        if (BIAS) v += bv;
        if (GELU_) v = fast_gelu(v);
        if (RESID) v += bf2f(resid[(size_t)row * N + col]);
        Cout[(size_t)row * N + col] = f2bf(v);
      }
    }
  }
#undef READ_A_KS
#undef READ_B_KS
#undef MFMA_Q
#undef PSYNC
#undef PSYNC_V
}

// --------- per-batch sim precompute: psim[b] = (norm(s_b)*SBOOST2)(...)^T ---------
__global__ __launch_bounds__(256) void simpre_kernel(
    const u16* __restrict__ qkvb, u16* __restrict__ psim) {
  __shared__ u16 sln[128][200];
  int b = blockIdx.x, tid = threadIdx.x;
  {
    int row = tid >> 1, half = tid & 1;
    const u16* sr = qkvb + ((size_t)(b * K + row)) * QKVW + SIMOFF + half * 96;
    u16 v[96];
    float sq = 0.f;
#pragma unroll
    for (int j = 0; j < 12; ++j) {
      uint4 u4 = *(const uint4*)(sr + j * 8);
      u32 uu[4] = {u4.x, u4.y, u4.z, u4.w};
#pragma unroll
      for (int t = 0; t < 4; ++t) {
        v[j * 8 + 2 * t] = (u16)(uu[t] & 0xffffu);
        v[j * 8 + 2 * t + 1] = (u16)(uu[t] >> 16);
      }
    }
#pragma unroll
    for (int j = 0; j < 96; ++j) { float f = bf2f(v[j]); sq += f * f; }
    sq += __shfl_xor(sq, 1, 64);
    float inv = SBOOST2 / fmaxf(sqrtf(sq), 1e-12f);
#pragma unroll
    for (int j = 0; j < 96; ++j) sln[row][half * 96 + j] = f2bf(bf2f(v[j]) * inv);
  }
  __syncthreads();
  int w = tid >> 6, lane = tid & 63;
  int lr = lane & 15, lg = lane >> 4;
  int q0 = 32 * w;
  f32x4 accs[2][8] = {};
#pragma unroll
  for (int ks = 0; ks < 6; ++ks) {
    bf16x8 af[2];
#pragma unroll
    for (int m = 0; m < 2; ++m)
      af[m] = *(const bf16x8*)(&sln[q0 + 16 * m + lr][ks * 32 + lg * 8]);
#pragma unroll
    for (int n = 0; n < 8; ++n) {
      bf16x8 bf = *(const bf16x8*)(&sln[16 * n + lr][ks * 32 + lg * 8]);
#pragma unroll
      for (int m = 0; m < 2; ++m)
        accs[m][n] = __builtin_amdgcn_mfma_f32_16x16x32_bf16(af[m], bf, accs[m][n], 0, 0, 0);
    }
  }
  u16* pb = psim + (size_t)b * K * K;
#pragma unroll
  for (int m = 0; m < 2; ++m)
#pragma unroll
    for (int n = 0; n < 8; ++n)
#pragma unroll
      for (int r = 0; r < 4; ++r)
        pb[(size_t)(q0 + 16 * m + 4 * lg + r) * K + 16 * n + lr] = f2bf(accs[m][n][r]);
}

// ---------------- MFMA attention: one block per (b,h), 4 waves x 32 q-rows ----------------
// K now staged into LDS (r12 lesson: row-strided fragment reads from global are
// 16-line divergent gathers; LDS converts to coalesced stage + 2-way-bank reads).
__global__ __launch_bounds__(256) void attn_kernel(
    const u16* __restrict__ qkv, const u16* __restrict__ psim,
    u16* __restrict__ ob) {
  __shared__ u16 Vt[96][136];
  __shared__ u16 Pl[4][32][136];
  __shared__ u16 Kt[128][104];  // +8 pad: row stride 208B = 52 dw = bank+20 -> 2-way (free)
  int bh = blockIdx.x, b = bh >> 3, h = bh & 7;
  int tid = threadIdx.x, w = tid >> 6, lane = tid & 63;
  int lr = lane & 15, lg = lane >> 4;
  const u16* qb = qkv + (size_t)b * K * QKVW + h * HD;
  const u16* kb = qb + D;
  const u16* vb = qb + 2 * D;
  // stage V transposed
  for (int idx = tid; idx < 128 * 12; idx += 256) {
    int r = idx / 12, db = idx - r * 12;
    uint4 v4 = *(const uint4*)(vb + (size_t)r * QKVW + db * 8);
    u32 vv[4] = {v4.x, v4.y, v4.z, v4.w};
#pragma unroll
    for (int j = 0; j < 4; ++j) {
      Vt[db * 8 + 2 * j][r] = (u16)(vv[j] & 0xffffu);
      Vt[db * 8 + 2 * j + 1][r] = (u16)(vv[j] >> 16);
    }
  }
  // stage K row-major (coalesced 16B per thread)
  for (int idx = tid; idx < 128 * 12; idx += 256) {
    int r = idx / 12, db = idx - r * 12;
    *(uint4*)(&Kt[r][db * 8]) = *(const uint4*)(kb + (size_t)r * QKVW + db * 8);
  }
  // stage sim tile into the Pl region ([128][136] view); each wave later
  // reads/overwrites only its own 32 rows (wave-local after the sync).
  u16* siml = &Pl[0][0][0];
  {
    const u16* pb = psim + (size_t)b * K * K;
    for (int c = tid; c < 2048; c += 256) {
      int r = c >> 4, cc = c & 15;
      *(uint4*)(siml + r * 136 + cc * 8) = *(const uint4*)(pb + r * 128 + cc * 8);
    }
  }
  __syncthreads();
  int q0 = 32 * w;
  // acc init from sim (C/D fragment layout: row=16m+4lg+r, col=16n+lr)
  f32x4 accs[2][8];
#pragma unroll
  for (int m = 0; m < 2; ++m)
#pragma unroll
    for (int n = 0; n < 8; ++n)
#pragma unroll
      for (int r = 0; r < 4; ++r)
        accs[m][n][r] = bf2f(siml[(q0 + 16 * m + 4 * lg + r) * 136 + 16 * n + lr]);
  // QK^T (Q pre-scaled by QSCALE in weights); K from LDS
#pragma unroll
  for (int ks = 0; ks < 3; ++ks) {
    bf16x8 af[2];
#pragma unroll
    for (int m = 0; m < 2; ++m)
      af[m] = *(const bf16x8*)(qb + (size_t)(q0 + 16 * m + lr) * QKVW + ks * 32 + lg * 8);
#pragma unroll
    for (int n = 0; n < 8; ++n) {
      bf16x8 bf = *(const bf16x8*)(&Kt[16 * n + lr][ks * 32 + lg * 8]);
#pragma unroll
      for (int m = 0; m < 2; ++m)
        accs[m][n] = __builtin_amdgcn_mfma_f32_16x16x32_bf16(af[m], bf, accs[m][n], 0, 0, 0);
    }
  }
  // softmax (exp2 domain) + write P
#pragma unroll
  for (int m = 0; m < 2; ++m) {
    float mx[4] = {-3e38f, -3e38f, -3e38f, -3e38f};
#pragma unroll
    for (int n = 0; n < 8; ++n)
#pragma unroll
      for (int r = 0; r < 4; ++r) mx[r] = fmaxf(mx[r], accs[m][n][r]);
#pragma unroll
    for (int r = 0; r < 4; ++r) {
      mx[r] = fmaxf(mx[r], __shfl_xor(mx[r], 1, 64));
      mx[r] = fmaxf(mx[r], __shfl_xor(mx[r], 2, 64));
      mx[r] = fmaxf(mx[r], __shfl_xor(mx[r], 4, 64));
      mx[r] = fmaxf(mx[r], __shfl_xor(mx[r], 8, 64));
    }
    float sm[4] = {0.f, 0.f, 0.f, 0.f};
#pragma unroll
    for (int n = 0; n < 8; ++n)
#pragma unroll
      for (int r = 0; r < 4; ++r) {
        float e = __builtin_amdgcn_exp2f(accs[m][n][r] - mx[r]);
        accs[m][n][r] = e;
        sm[r] += e;
      }
#pragma unroll
    for (int r = 0; r < 4; ++r) {
      sm[r] += __shfl_xor(sm[r], 1, 64);
      sm[r] += __shfl_xor(sm[r], 2, 64);
      sm[r] += __shfl_xor(sm[r], 4, 64);
      sm[r] += __shfl_xor(sm[r], 8, 64);
    }
    float inv[4];
#pragma unroll
    for (int r = 0; r < 4; ++r) inv[r] = 1.0f / sm[r];
#pragma unroll
    for (int n = 0; n < 8; ++n)
#pragma unroll
      for (int r = 0; r < 4; ++r)
        Pl[w][16 * m + 4 * lg + r][16 * n + lr] = f2bf(accs[m][n][r] * inv[r]);
  }
  __syncthreads();
  // PV
  f32x4 acco[2][6] = {};
#pragma unroll
  for (int ks = 0; ks < 4; ++ks) {
    bf16x8 pa[2];
#pragma unroll
    for (int m = 0; m < 2; ++m)
      pa[m] = *(const bf16x8*)(&Pl[w][16 * m + lr][ks * 32 + lg * 8]);
#pragma unroll
    for (int n = 0; n < 6; ++n) {
      bf16x8 bv = *(const bf16x8*)(&Vt[16 * n + lr][ks * 32 + lg * 8]);
#pragma unroll
      for (int m = 0; m < 2; ++m)
        acco[m][n] = __builtin_amdgcn_mfma_f32_16x16x32_bf16(pa[m], bv, acco[m][n], 0, 0, 0);
    }
  }
  u16* obb = ob + (size_t)b * K * D + h * HD;
#pragma unroll
  for (int m = 0; m < 2; ++m)
#pragma unroll
    for (int n = 0; n < 6; ++n)
#pragma unroll
      for (int r = 0; r < 4; ++r)
        obb[(size_t)(q0 + 16 * m + 4 * lg + r) * D + 16 * n + lr] = f2bf(acco[m][n][r]);
}

// ---------------- host ----------------
extern "C" void kernel_launch(void* const* d_in, const int* in_sizes, int n_in,
                              void* d_out, int out_size, void* d_ws, size_t ws_size,
                              hipStream_t stream) {
  (void)in_sizes; (void)n_in; (void)out_size;
  const float* slots = (const float*)d_in[0];
  const float* pos   = (const float*)d_in[1];
  const float* Wq    = (const float*)d_in[2];
  const float* Wk    = (const float*)d_in[3];
  const float* Wv    = (const float*)d_in[4];
  const float* Wo    = (const float*)d_in[5];
  const float* bo    = (const float*)d_in[6];
  const float* Wsim  = (const float*)d_in[7];
  const float* g1    = (const float*)d_in[8];
  const float* b1    = (const float*)d_in[9];
  const float* g2    = (const float*)d_in[10];
  const float* b2    = (const float*)d_in[11];
  const float* Wff1  = (const float*)d_in[12];
  const float* bff1  = (const float*)d_in[13];
  const float* Wff2  = (const float*)d_in[14];
  const float* bff2  = (const float*)d_in[15];
  const float* gf    = (const float*)d_in[16];
  const float* bfin  = (const float*)d_in[17];

  char* p = (char*)d_ws;
  u16*   x    = (u16*)p;   p += (size_t)M * D * 2;          // 25.2 MB
  u16*   nx   = (u16*)p;   p += (size_t)M * D * 2;          // 25.2 MB
  u16*   qkvb = (u16*)p;   p += (size_t)M * QKVW * 2;       // 83.9 MB
  u16*   ob   = (u16*)p;   p += (size_t)M * D * 2;          // 25.2 MB
  u16*   psim = (u16*)p;   p += (size_t)B * K * K * 2;      // 4.2 MB
  u16*   wtA4 = (u16*)p;   p += (size_t)4 * QKVW * D * 2;   // 15.7 MB
  u16*   wtB4 = (u16*)p;   p += (size_t)4 * D * D * 2;      // 4.7 MB
  u16*   wtC4 = (u16*)p;   p += (size_t)4 * FFD * D * 2;    // 18.9 MB
  u16*   wtD4 = (u16*)p;   p += (size_t)4 * D * FFD * 2;    // 18.9 MB
  if ((size_t)(p - (char*)d_ws) > ws_size) return;          // 221.8 MB <= proven 222.3
  u16* hb = qkvb;  // [M][3072] ffn hidden (spans qkvb+ob = 109 MB >= 100.7 MB)

  addpos_kernel<<<M * D / 256, 256, 0, stream>>>(slots, pos, x);
  WAll wp = {Wq, Wk, Wv, Wo, Wsim, Wff1, Wff2, wtA4, wtB4, wtC4, wtD4};
  wconv_all_kernel<<<28224, 256, 0, stream>>>(wp, QSCALE);

  int nbx_qkv = QKVW / 256, nwg_qkv = nbx_qkv * (M / 256);  // 10 x 64 = 640
  int nbx_o   = D / 256,    nwg_o   = nbx_o * (M / 256);    // 3 x 64 = 192
  int nbx_f1  = FFD / 256,  nwg_f1  = nbx_f1 * (M / 256);   // 12 x 64 = 768

  for (int l = 0; l < NL; ++l) {
    ln_kernel<true><<<M, 256, 0, stream>>>(x, g1 + l * D, b1 + l * D, nx);
    gemm256_kernel<false, false, false><<<nwg_qkv, 512, 0, stream>>>(
        nx, wtA4 + (size_t)l * QKVW * D, nullptr, nullptr, qkvb, QKVW, D, nbx_qkv);
    simpre_kernel<<<B, 256, 0, stream>>>(qkvb, psim);
    attn_kernel<<<B * NH, 256, 0, stream>>>(qkvb, psim, ob);
    gemm256_kernel<true, false, true><<<nwg_o, 512, 0, stream>>>(
        ob, wtB4 + (size_t)l * D * D, bo + l * D, x, x, D, D, nbx_o);
    ln_kernel<true><<<M, 256, 0, stream>>>(x, g2 + l * D, b2 + l * D, nx);
    gemm256_kernel<true, true, false><<<nwg_f1, 512, 0, stream>>>(
        nx, wtC4 + (size_t)l * FFD * D, bff1 + l * FFD, nullptr, hb, FFD, D, nbx_f1);
    gemm256_kernel<true, false, true><<<nwg_o, 512, 0, stream>>>(
        hb, wtD4 + (size_t)l * D * FFD, bff2 + l * D, x, x, D, FFD, nbx_o);
  }
  ln_kernel<false><<<M, 256, 0, stream>>>(x, gf, bfin, d_out);
}

// Round 14
// 1378.942 us; speedup vs baseline: 1.5581x; 1.0421x over previous
//
#include <hip/hip_runtime.h>

typedef unsigned short u16;
typedef unsigned int u32;
typedef float f32x4 __attribute__((ext_vector_type(4)));
typedef __bf16 bf16x8 __attribute__((ext_vector_type(8)));

static constexpr int D = 768, FFD = 3072, SIMC = 192, NH = 8, HD = 96;
static constexpr int B = 128, K = 128, M = B * K, NL = 4;
static constexpr int QKVW = 2560;   // q(768) k(768) v(768) s(192) pad(64)
static constexpr int SIMOFF = 2304;
// Q pre-scale = HD^-0.5 * log2(e)  (softmax runs in exp2 domain)
static constexpr float QSCALE = 0.14724502f;
// s pre-scale = sqrt(BOOST * log2(e))
static constexpr float SBOOST2 = 0.6578821f;
static constexpr float EPS_F = 1e-5f;

__device__ __forceinline__ float bf2f(u16 u) {
  union { u32 i; float f; } v; v.i = ((u32)u) << 16; return v.f;
}
__device__ __forceinline__ u16 f2bf(float f) {
  union { float f; u32 i; } v; v.f = f;
  u32 u = v.i;
  u32 r = (u + 0x7FFFu + ((u >> 16) & 1u)) >> 16;
  return (u16)r;
}

// tanh-form GELU via v_exp_f32/v_rcp_f32; max |err| vs erf-GELU ~3e-3.
__device__ __forceinline__ float fast_gelu(float x) {
  float u2 = x * (2.3020585f + 0.102944f * x * x);
  float e = __builtin_amdgcn_exp2f(u2);
  float r = __builtin_amdgcn_rcpf(1.0f + e);
  return x - x * r;
}

__device__ __forceinline__ void gload16(const void* g, void* l) {
  __builtin_amdgcn_global_load_lds(
      (const __attribute__((address_space(1))) void*)g,
      (__attribute__((address_space(3))) void*)l, 16, 0, 0);
}

// ---------------- add positional embedding (x is bf16 residual stream) ----------------
__global__ __launch_bounds__(256) void addpos_kernel(
    const float* __restrict__ slots, const float* __restrict__ pos,
    u16* __restrict__ x) {
  int i = blockIdx.x * 256 + threadIdx.x;
  int m = i / D;
  int d = i - m * D;
  x[i] = f2bf(slots[i] + pos[(m & (K - 1)) * D + d]);
}

// ---------------- layernorm (bf16 in; bf16 or f32 out) ----------------
__device__ __forceinline__ float block_sum(float v, float* sbuf) {
#pragma unroll
  for (int off = 32; off > 0; off >>= 1) v += __shfl_xor(v, off, 64);
  int lane = threadIdx.x & 63, w = threadIdx.x >> 6;
  if (lane == 0) sbuf[w] = v;
  __syncthreads();
  v = sbuf[0] + sbuf[1] + sbuf[2] + sbuf[3];
  __syncthreads();
  return v;
}

template <bool OUT_BF16>
__global__ __launch_bounds__(256) void ln_kernel(
    const u16* __restrict__ x, const float* __restrict__ g,
    const float* __restrict__ b, void* __restrict__ out) {
  __shared__ float sbuf[4];
  int row = blockIdx.x, tid = threadIdx.x;
  const u16* xr = x + (size_t)row * D;
  float v0 = bf2f(xr[tid]), v1 = bf2f(xr[tid + 256]), v2 = bf2f(xr[tid + 512]);
  float s = block_sum(v0 + v1 + v2, sbuf);
  float mean = s * (1.0f / D);
  float d0 = v0 - mean, d1 = v1 - mean, d2 = v2 - mean;
  float sq = block_sum(d0 * d0 + d1 * d1 + d2 * d2, sbuf);
  float rs = rsqrtf(sq * (1.0f / D) + EPS_F);
  float y0 = d0 * rs * g[tid] + b[tid];
  float y1 = d1 * rs * g[tid + 256] + b[tid + 256];
  float y2 = d2 * rs * g[tid + 512] + b[tid + 512];
  if (OUT_BF16) {
    u16* o = (u16*)out + (size_t)row * D;
    o[tid] = f2bf(y0); o[tid + 256] = f2bf(y1); o[tid + 512] = f2bf(y2);
  } else {
    float* o = (float*)out + (size_t)row * D;
    o[tid] = y0; o[tid + 256] = y1; o[tid + 512] = y2;
  }
}

// ------ ALL 4 layers' weight transposes+converts in ONE launch (hoisted) ------
struct WAll {
  const float *wq, *wk, *wv, *wo, *wsim, *wff1, *wff2;
  u16 *tA, *tB, *tC, *tD;
};
__global__ __launch_bounds__(256) void wconv_all_kernel(WAll p, float qscale) {
  __shared__ u16 t[32][33];
  int bid = blockIdx.x;
  int l = bid / 7056, b = bid - l * 7056;
  const float* W; u16* Wt; int N, Kd, n0, k0;
  float sc = 1.0f;
  if (b < 2304) {
    int z = b / 576, rem = b - z * 576;
    N = 768; Kd = 768;
    n0 = (rem % 24) * 32; k0 = (rem / 24) * 32;
    if (z == 0) { W = p.wq + (size_t)l * 589824; Wt = p.tA + (size_t)l * 1966080; sc = qscale; }
    else if (z == 1) { W = p.wk + (size_t)l * 589824; Wt = p.tA + (size_t)l * 1966080 + 589824; }
    else if (z == 2) { W = p.wv + (size_t)l * 589824; Wt = p.tA + (size_t)l * 1966080 + 1179648; }
    else { W = p.wo + (size_t)l * 589824; Wt = p.tB + (size_t)l * 589824; }
  } else if (b < 2448) {
    int rem = b - 2304;
    W = p.wsim + (size_t)l * 147456;
    Wt = p.tA + (size_t)l * 1966080 + (size_t)SIMOFF * 768;
    N = SIMC; Kd = 768;
    n0 = (rem % 6) * 32; k0 = (rem / 6) * 32;
  } else if (b < 4752) {
    int rem = b - 2448;
    W = p.wff1 + (size_t)l * 2359296; Wt = p.tC + (size_t)l * 2359296;
    N = FFD; Kd = 768;
    n0 = (rem % 96) * 32; k0 = (rem / 96) * 32;
  } else {
    int rem = b - 4752;
    W = p.wff2 + (size_t)l * 2359296; Wt = p.tD + (size_t)l * 2359296;
    N = 768; Kd = FFD;
    n0 = (rem % 24) * 32; k0 = (rem / 24) * 32;
  }
  int tid = threadIdx.x;
  int c = tid & 31, r4 = tid >> 5;
#pragma unroll
  for (int i = 0; i < 4; ++i) {
    int r = r4 + i * 8;
    t[r][c] = f2bf(W[(size_t)(k0 + r) * N + n0 + c] * sc);
  }
  __syncthreads();
#pragma unroll
  for (int i = 0; i < 4; ++i) {
    int r = r4 + i * 8;
    Wt[(size_t)(n0 + r) * Kd + k0 + c] = t[c][r];
  }
}

// ===================== 256x256 4-phase GEMM (verified r11) =====================
// See r11 comments: ledger verified; B in LDS; XOR swizzle per rule 21.
template <bool BIAS, bool GELU_, bool RESID>
__global__ __launch_bounds__(512, 2) void gemm256_kernel(
    const u16* __restrict__ A, const u16* __restrict__ Bt,
    const float* __restrict__ bias, const u16* __restrict__ resid,
    u16* __restrict__ Cout, int N, int Kdim, int NBX) {
  __shared__ u16 lds[65536];
  int tid = threadIdx.x;
  int w = tid >> 6, lane = tid & 63;
  int wm = w >> 2, wn = w & 3;
  int lr = lane & 15, lg = lane >> 4;

  int nwg = gridDim.x;
  int cpx = nwg >> 3;
  int swz = (blockIdx.x & 7) * cpx + (blockIdx.x >> 3);
  int bx = swz % NBX, by = swz / NBX;
  int n0 = bx << 8, m0 = by << 8;

  int scol = ((lane & 7) ^ (lane >> 3)) << 3;
  size_t aOff = (size_t)((w << 4) + (lane >> 3)) * Kdim + scol;
  u16* ldsU = lds;

  auto stageA = [&](int buf, int h, int t) {
    const u16* g = A + (size_t)(m0 + (h << 7)) * Kdim + ((size_t)t << 6) + aOff;
    u16* l = ldsU + buf * 32768 + h * 8192 + (w << 10);
    gload16(g, l);
    gload16(g + ((size_t)Kdim << 3), l + 512);
  };
  auto stageB = [&](int buf, int h, int t) {
    const u16* g = Bt + (size_t)(n0 + (h << 7)) * Kdim + ((size_t)t << 6) + aOff;
    u16* l = ldsU + buf * 32768 + 16384 + h * 8192 + (w << 10);
    gload16(g, l);
    gload16(g + ((size_t)Kdim << 3), l + 512);
  };

  const u16* lA0p = ldsU;
  const u16* lB0p = ldsU + 16384;
  const u16* lA1p = ldsU + 32768;
  const u16* lB1p = ldsU + 49152;
  int arow = (wm * 128 + lr) * 64;
  int brow = (wn * 64 + lr) * 64;
  int swz0 = (((lg * 16)) ^ ((lr & 7) << 4)) >> 1;
  int swz1 = ((64 + lg * 16) ^ ((lr & 7) << 4)) >> 1;

  f32x4 acc[8][4] = {};
  bf16x8 ar[2][4], br[2][4];

#define READ_A_KS(BASE, MSEG, KS)                                            \
  do {                                                                       \
    _Pragma("unroll") for (int mm = 0; mm < 4; ++mm) {                       \
      const u16* p_ = (BASE) + arow + ((MSEG) * 64 + mm * 16) * 64;          \
      ar[KS][mm] = *(const bf16x8*)(p_ + ((KS) ? swz1 : swz0));              \
    }                                                                        \
  } while (0)
#define READ_B_KS(BASE, NSEG, KS)                                            \
  do {                                                                       \
    _Pragma("unroll") for (int nn = 0; nn < 2; ++nn) {                       \
      const u16* p_ = (BASE) + brow + ((NSEG) * 32 + nn * 16) * 64;          \
      br[KS][(NSEG) * 2 + nn] = *(const bf16x8*)(p_ + ((KS) ? swz1 : swz0)); \
    }                                                                        \
  } while (0)
#define MFMA_Q(MSEG, NSEG)                                                   \
  do {                                                                       \
    __builtin_amdgcn_s_setprio(1);                                           \
    _Pragma("unroll") for (int ks = 0; ks < 2; ++ks)                         \
      _Pragma("unroll") for (int mm = 0; mm < 4; ++mm)                       \
        _Pragma("unroll") for (int nn = 0; nn < 2; ++nn)                     \
          acc[(MSEG) * 4 + mm][(NSEG) * 2 + nn] =                            \
              __builtin_amdgcn_mfma_f32_16x16x32_bf16(                       \
                  ar[ks][mm], br[ks][(NSEG) * 2 + nn],                       \
                  acc[(MSEG) * 4 + mm][(NSEG) * 2 + nn], 0, 0, 0);           \
    __builtin_amdgcn_s_setprio(0);                                           \
  } while (0)
#define PSYNC()                                                              \
  do {                                                                       \
    __builtin_amdgcn_sched_barrier(0);                                       \
    asm volatile("s_waitcnt lgkmcnt(0)" ::: "memory");                       \
    __builtin_amdgcn_s_barrier();                                            \
    __builtin_amdgcn_sched_barrier(0);                                       \
  } while (0)
#define PSYNC_V(N)                                                           \
  do {                                                                       \
    __builtin_amdgcn_sched_barrier(0);                                       \
    asm volatile("s_waitcnt vmcnt(" #N ") lgkmcnt(0)" ::: "memory");         \
    __builtin_amdgcn_s_barrier();                                            \
    __builtin_amdgcn_sched_barrier(0);                                       \
  } while (0)

  int NK = Kdim >> 6, NI = NK >> 1;
  // prologue: tile0 -> buf0 (A+B), tile1 B -> buf1
  stageA(0, 0, 0); stageA(0, 1, 0); stageB(0, 0, 0); stageB(0, 1, 0);
  stageB(1, 0, 1); stageB(1, 1, 1);
  asm volatile("s_waitcnt vmcnt(4)" ::: "memory");
  __builtin_amdgcn_s_barrier();
  __builtin_amdgcn_sched_barrier(0);

  for (int i = 0; i < NI; ++i) {
    int t1 = 2 * i + 1, t2 = 2 * i + 2, t3 = 2 * i + 3;
    bool last = (i == NI - 1);
    // ---- P1 ----
    stageA(1, 0, t1); stageA(1, 1, t1);
    READ_A_KS(lA0p, 0, 0); READ_B_KS(lB0p, 0, 0); READ_B_KS(lB0p, 1, 0);
    READ_A_KS(lA0p, 0, 1); READ_B_KS(lB0p, 0, 1); READ_B_KS(lB0p, 1, 1);
    MFMA_Q(0, 0); MFMA_Q(0, 1);
    PSYNC();
    // ---- P2 ----
    if (!last) { stageB(0, 0, t2); stageB(0, 1, t2); }
    READ_A_KS(lA0p, 1, 0); READ_A_KS(lA0p, 1, 1);
    MFMA_Q(1, 0); MFMA_Q(1, 1);
    if (last) PSYNC_V(0);
    else      PSYNC_V(4);
    // ---- P3 ----
    if (!last) { stageA(0, 0, t2); stageA(0, 1, t2); }
    READ_A_KS(lA1p, 0, 0); READ_B_KS(lB1p, 0, 0); READ_B_KS(lB1p, 1, 0);
    READ_A_KS(lA1p, 0, 1); READ_B_KS(lB1p, 0, 1); READ_B_KS(lB1p, 1, 1);
    MFMA_Q(0, 0); MFMA_Q(0, 1);
    PSYNC();
    // ---- P4 ----
    if (!last) { stageB(1, 0, t3); stageB(1, 1, t3); }
    READ_A_KS(lA1p, 1, 0); READ_A_KS(lA1p, 1, 1);
    MFMA_Q(1, 0); MFMA_Q(1, 1);
    if (last) PSYNC();
    else      PSYNC_V(4);
  }

  // ---- epilogue ----
#pragma unroll
  for (int m = 0; m < 8; ++m) {
#pragma unroll
    for (int n = 0; n < 4; ++n) {
      int col = n0 + wn * 64 + n * 16 + lr;
      float bv = BIAS ? bias[col] : 0.0f;
#pragma unroll
      for (int r = 0; r < 4; ++r) {
        int row = m0 + wm * 128 + m * 16 + lg * 4 + r;
        float v = acc[m][n][r];
        if (BIAS) v += bv;
        if (GELU_) v = fast_gelu(v);
        if (RESID) v += bf2f(resid[(size_t)row * N + col]);
        Cout[(size_t)row * N + col] = f2bf(v);
      }
    }
  }
#undef READ_A_KS
#undef READ_B_KS
#undef MFMA_Q
#undef PSYNC
#undef PSYNC_V
}

// --------- per-batch sim precompute: psim[b] = (norm(s_b)*SBOOST2)(...)^T ---------
__global__ __launch_bounds__(256) void simpre_kernel(
    const u16* __restrict__ qkvb, u16* __restrict__ psim) {
  __shared__ u16 sln[128][200];
  int b = blockIdx.x, tid = threadIdx.x;
  {
    int row = tid >> 1, half = tid & 1;
    const u16* sr = qkvb + ((size_t)(b * K + row)) * QKVW + SIMOFF + half * 96;
    u16 v[96];
    float sq = 0.f;
#pragma unroll
    for (int j = 0; j < 12; ++j) {
      uint4 u4 = *(const uint4*)(sr + j * 8);
      u32 uu[4] = {u4.x, u4.y, u4.z, u4.w};
#pragma unroll
      for (int t = 0; t < 4; ++t) {
        v[j * 8 + 2 * t] = (u16)(uu[t] & 0xffffu);
        v[j * 8 + 2 * t + 1] = (u16)(uu[t] >> 16);
      }
    }
#pragma unroll
    for (int j = 0; j < 96; ++j) { float f = bf2f(v[j]); sq += f * f; }
    sq += __shfl_xor(sq, 1, 64);
    float inv = SBOOST2 / fmaxf(sqrtf(sq), 1e-12f);
#pragma unroll
    for (int j = 0; j < 96; ++j) sln[row][half * 96 + j] = f2bf(bf2f(v[j]) * inv);
  }
  __syncthreads();
  int w = tid >> 6, lane = tid & 63;
  int lr = lane & 15, lg = lane >> 4;
  int q0 = 32 * w;
  f32x4 accs[2][8] = {};
#pragma unroll
  for (int ks = 0; ks < 6; ++ks) {
    bf16x8 af[2];
#pragma unroll
    for (int m = 0; m < 2; ++m)
      af[m] = *(const bf16x8*)(&sln[q0 + 16 * m + lr][ks * 32 + lg * 8]);
#pragma unroll
    for (int n = 0; n < 8; ++n) {
      bf16x8 bf = *(const bf16x8*)(&sln[16 * n + lr][ks * 32 + lg * 8]);
#pragma unroll
      for (int m = 0; m < 2; ++m)
        accs[m][n] = __builtin_amdgcn_mfma_f32_16x16x32_bf16(af[m], bf, accs[m][n], 0, 0, 0);
    }
  }
  u16* pb = psim + (size_t)b * K * K;
#pragma unroll
  for (int m = 0; m < 2; ++m)
#pragma unroll
    for (int n = 0; n < 8; ++n)
#pragma unroll
      for (int r = 0; r < 4; ++r)
        pb[(size_t)(q0 + 16 * m + 4 * lg + r) * K + 16 * n + lr] = f2bf(accs[m][n][r]);
}

// ---------------- MFMA attention: one block per (b,h), 4 waves x 32 q-rows ----------------
// K staged into the Pl REGION (occupancy-neutral: LDS stays 60.9KB -> 2 blocks/CU).
// QK^T reads K from LDS; sim bias added from global psim (L2-resident) during
// softmax; after a barrier the P writes overwrite the K region.
__global__ __launch_bounds__(256) void attn_kernel(
    const u16* __restrict__ qkv, const u16* __restrict__ psim,
    u16* __restrict__ ob) {
  __shared__ u16 Vt[96][136];
  __shared__ u16 Pl[4][32][136];  // holds K [128][104] until P overwrites it
  int bh = blockIdx.x, b = bh >> 3, h = bh & 7;
  int tid = threadIdx.x, w = tid >> 6, lane = tid & 63;
  int lr = lane & 15, lg = lane >> 4;
  const u16* qb = qkv + (size_t)b * K * QKVW + h * HD;
  const u16* kb = qb + D;
  const u16* vb = qb + 2 * D;
  // stage V transposed
  for (int idx = tid; idx < 128 * 12; idx += 256) {
    int r = idx / 12, db = idx - r * 12;
    uint4 v4 = *(const uint4*)(vb + (size_t)r * QKVW + db * 8);
    u32 vv[4] = {v4.x, v4.y, v4.z, v4.w};
#pragma unroll
    for (int j = 0; j < 4; ++j) {
      Vt[db * 8 + 2 * j][r] = (u16)(vv[j] & 0xffffu);
      Vt[db * 8 + 2 * j + 1][r] = (u16)(vv[j] >> 16);
    }
  }
  // stage K row-major into Pl region as [128][104] (coalesced 16B per thread;
  // stride 104 u16 = 52 dw -> uniform 8 accesses/bank on b128 reads = optimal)
  u16* Kl = &Pl[0][0][0];
  for (int idx = tid; idx < 128 * 12; idx += 256) {
    int r = idx / 12, db = idx - r * 12;
    *(uint4*)(Kl + r * 104 + db * 8) = *(const uint4*)(kb + (size_t)r * QKVW + db * 8);
  }
  __syncthreads();
  int q0 = 32 * w;
  // QK^T (Q pre-scaled by QSCALE in weights); K from LDS; acc starts at 0
  f32x4 accs[2][8] = {};
#pragma unroll
  for (int ks = 0; ks < 3; ++ks) {
    bf16x8 af[2];
#pragma unroll
    for (int m = 0; m < 2; ++m)
      af[m] = *(const bf16x8*)(qb + (size_t)(q0 + 16 * m + lr) * QKVW + ks * 32 + lg * 8);
#pragma unroll
    for (int n = 0; n < 8; ++n) {
      bf16x8 bf = *(const bf16x8*)(Kl + (16 * n + lr) * 104 + ks * 32 + lg * 8);
#pragma unroll
      for (int m = 0; m < 2; ++m)
        accs[m][n] = __builtin_amdgcn_mfma_f32_16x16x32_bf16(af[m], bf, accs[m][n], 0, 0, 0);
    }
  }
  __syncthreads();  // all waves' K reads complete before P overwrites the region
  // add sim bias from global psim (L2-resident; C/D layout row=q0+16m+4lg+r, col=16n+lr)
  const u16* pb = psim + (size_t)b * K * K;
#pragma unroll
  for (int m = 0; m < 2; ++m)
#pragma unroll
    for (int n = 0; n < 8; ++n)
#pragma unroll
      for (int r = 0; r < 4; ++r)
        accs[m][n][r] += bf2f(pb[(size_t)(q0 + 16 * m + 4 * lg + r) * 128 + 16 * n + lr]);
  // softmax (exp2 domain) + write P
#pragma unroll
  for (int m = 0; m < 2; ++m) {
    float mx[4] = {-3e38f, -3e38f, -3e38f, -3e38f};
#pragma unroll
    for (int n = 0; n < 8; ++n)
#pragma unroll
      for (int r = 0; r < 4; ++r) mx[r] = fmaxf(mx[r], accs[m][n][r]);
#pragma unroll
    for (int r = 0; r < 4; ++r) {
      mx[r] = fmaxf(mx[r], __shfl_xor(mx[r], 1, 64));
      mx[r] = fmaxf(mx[r], __shfl_xor(mx[r], 2, 64));
      mx[r] = fmaxf(mx[r], __shfl_xor(mx[r], 4, 64));
      mx[r] = fmaxf(mx[r], __shfl_xor(mx[r], 8, 64));
    }
    float sm[4] = {0.f, 0.f, 0.f, 0.f};
#pragma unroll
    for (int n = 0; n < 8; ++n)
#pragma unroll
      for (int r = 0; r < 4; ++r) {
        float e = __builtin_amdgcn_exp2f(accs[m][n][r] - mx[r]);
        accs[m][n][r] = e;
        sm[r] += e;
      }
#pragma unroll
    for (int r = 0; r < 4; ++r) {
      sm[r] += __shfl_xor(sm[r], 1, 64);
      sm[r] += __shfl_xor(sm[r], 2, 64);
      sm[r] += __shfl_xor(sm[r], 4, 64);
      sm[r] += __shfl_xor(sm[r], 8, 64);
    }
    float inv[4];
#pragma unroll
    for (int r = 0; r < 4; ++r) inv[r] = 1.0f / sm[r];
#pragma unroll
    for (int n = 0; n < 8; ++n)
#pragma unroll
      for (int r = 0; r < 4; ++r)
        Pl[w][16 * m + 4 * lg + r][16 * n + lr] = f2bf(accs[m][n][r] * inv[r]);
  }
  __syncthreads();
  // PV
  f32x4 acco[2][6] = {};
#pragma unroll
  for (int ks = 0; ks < 4; ++ks) {
    bf16x8 pa[2];
#pragma unroll
    for (int m = 0; m < 2; ++m)
      pa[m] = *(const bf16x8*)(&Pl[w][16 * m + lr][ks * 32 + lg * 8]);
#pragma unroll
    for (int n = 0; n < 6; ++n) {
      bf16x8 bv = *(const bf16x8*)(&Vt[16 * n + lr][ks * 32 + lg * 8]);
#pragma unroll
      for (int m = 0; m < 2; ++m)
        acco[m][n] = __builtin_amdgcn_mfma_f32_16x16x32_bf16(pa[m], bv, acco[m][n], 0, 0, 0);
    }
  }
  u16* obb = ob + (size_t)b * K * D + h * HD;
#pragma unroll
  for (int m = 0; m < 2; ++m)
#pragma unroll
    for (int n = 0; n < 6; ++n)
#pragma unroll
      for (int r = 0; r < 4; ++r)
        obb[(size_t)(q0 + 16 * m + 4 * lg + r) * D + 16 * n + lr] = f2bf(acco[m][n][r]);
}

// ---------------- host ----------------
extern "C" void kernel_launch(void* const* d_in, const int* in_sizes, int n_in,
                              void* d_out, int out_size, void* d_ws, size_t ws_size,
                              hipStream_t stream) {
  (void)in_sizes; (void)n_in; (void)out_size;
  const float* slots = (const float*)d_in[0];
  const float* pos   = (const float*)d_in[1];
  const float* Wq    = (const float*)d_in[2];
  const float* Wk    = (const float*)d_in[3];
  const float* Wv    = (const float*)d_in[4];
  const float* Wo    = (const float*)d_in[5];
  const float* bo    = (const float*)d_in[6];
  const float* Wsim  = (const float*)d_in[7];
  const float* g1    = (const float*)d_in[8];
  const float* b1    = (const float*)d_in[9];
  const float* g2    = (const float*)d_in[10];
  const float* b2    = (const float*)d_in[11];
  const float* Wff1  = (const float*)d_in[12];
  const float* bff1  = (const float*)d_in[13];
  const float* Wff2  = (const float*)d_in[14];
  const float* bff2  = (const float*)d_in[15];
  const float* gf    = (const float*)d_in[16];
  const float* bfin  = (const float*)d_in[17];

  char* p = (char*)d_ws;
  u16*   x    = (u16*)p;   p += (size_t)M * D * 2;          // 25.2 MB
  u16*   nx   = (u16*)p;   p += (size_t)M * D * 2;          // 25.2 MB
  u16*   qkvb = (u16*)p;   p += (size_t)M * QKVW * 2;       // 83.9 MB
  u16*   ob   = (u16*)p;   p += (size_t)M * D * 2;          // 25.2 MB
  u16*   psim = (u16*)p;   p += (size_t)B * K * K * 2;      // 4.2 MB
  u16*   wtA4 = (u16*)p;   p += (size_t)4 * QKVW * D * 2;   // 15.7 MB
  u16*   wtB4 = (u16*)p;   p += (size_t)4 * D * D * 2;      // 4.7 MB
  u16*   wtC4 = (u16*)p;   p += (size_t)4 * FFD * D * 2;    // 18.9 MB
  u16*   wtD4 = (u16*)p;   p += (size_t)4 * D * FFD * 2;    // 18.9 MB
  if ((size_t)(p - (char*)d_ws) > ws_size) return;          // 221.8 MB <= proven 222.3
  u16* hb = qkvb;  // [M][3072] ffn hidden (spans qkvb+ob = 109 MB >= 100.7 MB)

  addpos_kernel<<<M * D / 256, 256, 0, stream>>>(slots, pos, x);
  WAll wp = {Wq, Wk, Wv, Wo, Wsim, Wff1, Wff2, wtA4, wtB4, wtC4, wtD4};
  wconv_all_kernel<<<28224, 256, 0, stream>>>(wp, QSCALE);

  int nbx_qkv = QKVW / 256, nwg_qkv = nbx_qkv * (M / 256);  // 10 x 64 = 640
  int nbx_o   = D / 256,    nwg_o   = nbx_o * (M / 256);    // 3 x 64 = 192
  int nbx_f1  = FFD / 256,  nwg_f1  = nbx_f1 * (M / 256);   // 12 x 64 = 768

  for (int l = 0; l < NL; ++l) {
    ln_kernel<true><<<M, 256, 0, stream>>>(x, g1 + l * D, b1 + l * D, nx);
    gemm256_kernel<false, false, false><<<nwg_qkv, 512, 0, stream>>>(
        nx, wtA4 + (size_t)l * QKVW * D, nullptr, nullptr, qkvb, QKVW, D, nbx_qkv);
    simpre_kernel<<<B, 256, 0, stream>>>(qkvb, psim);
    attn_kernel<<<B * NH, 256, 0, stream>>>(qkvb, psim, ob);
    gemm256_kernel<true, false, true><<<nwg_o, 512, 0, stream>>>(
        ob, wtB4 + (size_t)l * D * D, bo + l * D, x, x, D, D, nbx_o);
    ln_kernel<true><<<M, 256, 0, stream>>>(x, g2 + l * D, b2 + l * D, nx);
    gemm256_kernel<true, true, false><<<nwg_f1, 512, 0, stream>>>(
        nx, wtC4 + (size_t)l * FFD * D, bff1 + l * FFD, nullptr, hb, FFD, D, nbx_f1);
    gemm256_kernel<true, false, true><<<nwg_o, 512, 0, stream>>>(
        hb, wtD4 + (size_t)l * D * FFD, bff2 + l * D, x, x, D, FFD, nbx_o);
  }
  ln_kernel<false><<<M, 256, 0, stream>>>(x, gf, bfin, d_out);
}

// Round 15
// 1321.131 us; speedup vs baseline: 1.6263x; 1.0438x over previous
//
#include <hip/hip_runtime.h>

typedef unsigned short u16;
typedef unsigned int u32;
typedef float f32x4 __attribute__((ext_vector_type(4)));
typedef __bf16 bf16x8 __attribute__((ext_vector_type(8)));

static constexpr int D = 768, FFD = 3072, SIMC = 192, NH = 8, HD = 96;
static constexpr int B = 128, K = 128, M = B * K, NL = 4;
static constexpr int QKVW = 2560;   // q(768) k(768) v(768) s(192) pad(64)
static constexpr int SIMOFF = 2304;
// Q pre-scale = HD^-0.5 * log2(e)  (softmax runs in exp2 domain)
static constexpr float QSCALE = 0.14724502f;
// s pre-scale = sqrt(BOOST * log2(e))
static constexpr float SBOOST2 = 0.6578821f;
static constexpr float EPS_F = 1e-5f;

__device__ __forceinline__ float bf2f(u16 u) {
  union { u32 i; float f; } v; v.i = ((u32)u) << 16; return v.f;
}
__device__ __forceinline__ u16 f2bf(float f) {
  union { float f; u32 i; } v; v.f = f;
  u32 u = v.i;
  u32 r = (u + 0x7FFFu + ((u >> 16) & 1u)) >> 16;
  return (u16)r;
}
__device__ __forceinline__ u32 pack2(float a, float b) {
  return (u32)f2bf(a) | ((u32)f2bf(b) << 16);
}

// tanh-form GELU via v_exp_f32/v_rcp_f32; max |err| vs erf-GELU ~3e-3.
__device__ __forceinline__ float fast_gelu(float x) {
  float u2 = x * (2.3020585f + 0.102944f * x * x);
  float e = __builtin_amdgcn_exp2f(u2);
  float r = __builtin_amdgcn_rcpf(1.0f + e);
  return x - x * r;
}

__device__ __forceinline__ void gload16(const void* g, void* l) {
  __builtin_amdgcn_global_load_lds(
      (const __attribute__((address_space(1))) void*)g,
      (__attribute__((address_space(3))) void*)l, 16, 0, 0);
}

// ---------------- layernorm: one WAVE per row, no LDS/barriers (G13) ----------------
// lane loads 12 contiguous bf16: uint4 at lane*8 (cols 0..511) + uint2 at 512+lane*4.
template <bool OUT_BF16>
__global__ __launch_bounds__(256) void ln_kernel(
    const u16* __restrict__ x, const float* __restrict__ g,
    const float* __restrict__ b, void* __restrict__ out) {
  int row = blockIdx.x * 4 + (threadIdx.x >> 6);
  int lane = threadIdx.x & 63;
  const u16* xr = x + (size_t)row * D;
  uint4 a = *(const uint4*)(xr + lane * 8);
  uint2 c = *(const uint2*)(xr + 512 + lane * 4);
  float v[12];
  u32 aa[4] = {a.x, a.y, a.z, a.w};
#pragma unroll
  for (int j = 0; j < 4; ++j) {
    v[2 * j] = bf2f((u16)(aa[j] & 0xffffu));
    v[2 * j + 1] = bf2f((u16)(aa[j] >> 16));
  }
  u32 cc[2] = {c.x, c.y};
#pragma unroll
  for (int j = 0; j < 2; ++j) {
    v[8 + 2 * j] = bf2f((u16)(cc[j] & 0xffffu));
    v[9 + 2 * j] = bf2f((u16)(cc[j] >> 16));
  }
  float s = 0.f;
#pragma unroll
  for (int j = 0; j < 12; ++j) s += v[j];
#pragma unroll
  for (int off = 32; off > 0; off >>= 1) s += __shfl_xor(s, off, 64);
  float mean = s * (1.0f / D);
  float sq = 0.f;
#pragma unroll
  for (int j = 0; j < 12; ++j) { float d0 = v[j] - mean; sq += d0 * d0; }
#pragma unroll
  for (int off = 32; off > 0; off >>= 1) sq += __shfl_xor(sq, off, 64);
  float rs = rsqrtf(sq * (1.0f / D) + EPS_F);
  float4 g0 = *(const float4*)(g + lane * 8);
  float4 g1 = *(const float4*)(g + lane * 8 + 4);
  float4 g2 = *(const float4*)(g + 512 + lane * 4);
  float4 b0 = *(const float4*)(b + lane * 8);
  float4 b1 = *(const float4*)(b + lane * 8 + 4);
  float4 b2 = *(const float4*)(b + 512 + lane * 4);
  float gv[12] = {g0.x, g0.y, g0.z, g0.w, g1.x, g1.y, g1.z, g1.w,
                  g2.x, g2.y, g2.z, g2.w};
  float bv[12] = {b0.x, b0.y, b0.z, b0.w, b1.x, b1.y, b1.z, b1.w,
                  b2.x, b2.y, b2.z, b2.w};
  float y[12];
#pragma unroll
  for (int j = 0; j < 12; ++j) y[j] = (v[j] - mean) * rs * gv[j] + bv[j];
  if (OUT_BF16) {
    u16* o = (u16*)out + (size_t)row * D;
    uint4 oa = {pack2(y[0], y[1]), pack2(y[2], y[3]),
                pack2(y[4], y[5]), pack2(y[6], y[7])};
    uint2 oc = {pack2(y[8], y[9]), pack2(y[10], y[11])};
    *(uint4*)(o + lane * 8) = oa;
    *(uint2*)(o + 512 + lane * 4) = oc;
  } else {
    float* o = (float*)out + (size_t)row * D;
    *(float4*)(o + lane * 8) = {y[0], y[1], y[2], y[3]};
    *(float4*)(o + lane * 8 + 4) = {y[4], y[5], y[6], y[7]};
    *(float4*)(o + 512 + lane * 4) = {y[8], y[9], y[10], y[11]};
  }
}

// ------ ALL 4 layers' weight transposes+converts + addpos in ONE launch ------
// bid < 28224: wconv (7056/layer, verified r11 decode).
// bid >= 28224: vectorized addpos (6144 blocks, 8 elems/thread).
struct WAll {
  const float *wq, *wk, *wv, *wo, *wsim, *wff1, *wff2;
  u16 *tA, *tB, *tC, *tD;
  const float *slots, *pos;
  u16* x;
};
__global__ __launch_bounds__(256) void wconv_all_kernel(WAll p, float qscale) {
  __shared__ u16 t[32][33];
  int bid = blockIdx.x;
  int tid = threadIdx.x;
  if (bid >= 28224) {
    int i8 = ((bid - 28224) * 256 + tid) * 8;
    int m = i8 / D;
    int d = i8 - m * D;
    int pd = (m & (K - 1)) * D + d;
    float4 s0 = *(const float4*)(p.slots + i8);
    float4 s1 = *(const float4*)(p.slots + i8 + 4);
    float4 p0 = *(const float4*)(p.pos + pd);
    float4 p1 = *(const float4*)(p.pos + pd + 4);
    uint4 o = {pack2(s0.x + p0.x, s0.y + p0.y), pack2(s0.z + p0.z, s0.w + p0.w),
               pack2(s1.x + p1.x, s1.y + p1.y), pack2(s1.z + p1.z, s1.w + p1.w)};
    *(uint4*)(p.x + i8) = o;
    return;
  }
  int l = bid / 7056, b = bid - l * 7056;
  const float* W; u16* Wt; int N, Kd, n0, k0;
  float sc = 1.0f;
  if (b < 2304) {
    int z = b / 576, rem = b - z * 576;
    N = 768; Kd = 768;
    n0 = (rem % 24) * 32; k0 = (rem / 24) * 32;
    if (z == 0) { W = p.wq + (size_t)l * 589824; Wt = p.tA + (size_t)l * 1966080; sc = qscale; }
    else if (z == 1) { W = p.wk + (size_t)l * 589824; Wt = p.tA + (size_t)l * 1966080 + 589824; }
    else if (z == 2) { W = p.wv + (size_t)l * 589824; Wt = p.tA + (size_t)l * 1966080 + 1179648; }
    else { W = p.wo + (size_t)l * 589824; Wt = p.tB + (size_t)l * 589824; }
  } else if (b < 2448) {
    int rem = b - 2304;
    W = p.wsim + (size_t)l * 147456;
    Wt = p.tA + (size_t)l * 1966080 + (size_t)SIMOFF * 768;
    N = SIMC; Kd = 768;
    n0 = (rem % 6) * 32; k0 = (rem / 6) * 32;
  } else if (b < 4752) {
    int rem = b - 2448;
    W = p.wff1 + (size_t)l * 2359296; Wt = p.tC + (size_t)l * 2359296;
    N = FFD; Kd = 768;
    n0 = (rem % 96) * 32; k0 = (rem / 96) * 32;
  } else {
    int rem = b - 4752;
    W = p.wff2 + (size_t)l * 2359296; Wt = p.tD + (size_t)l * 2359296;
    N = 768; Kd = FFD;
    n0 = (rem % 24) * 32; k0 = (rem / 24) * 32;
  }
  int c = tid & 31, r4 = tid >> 5;
#pragma unroll
  for (int i = 0; i < 4; ++i) {
    int r = r4 + i * 8;
    t[r][c] = f2bf(W[(size_t)(k0 + r) * N + n0 + c] * sc);
  }
  __syncthreads();
#pragma unroll
  for (int i = 0; i < 4; ++i) {
    int r = r4 + i * 8;
    Wt[(size_t)(n0 + r) * Kd + k0 + c] = t[c][r];
  }
}

// ===================== 256x256 4-phase GEMM (verified r11) =====================
// See r11 comments: ledger verified; B in LDS; XOR swizzle per rule 21.
template <bool BIAS, bool GELU_, bool RESID>
__global__ __launch_bounds__(512, 2) void gemm256_kernel(
    const u16* __restrict__ A, const u16* __restrict__ Bt,
    const float* __restrict__ bias, const u16* __restrict__ resid,
    u16* __restrict__ Cout, int N, int Kdim, int NBX) {
  __shared__ u16 lds[65536];
  int tid = threadIdx.x;
  int w = tid >> 6, lane = tid & 63;
  int wm = w >> 2, wn = w & 3;
  int lr = lane & 15, lg = lane >> 4;

  int nwg = gridDim.x;
  int cpx = nwg >> 3;
  int swz = (blockIdx.x & 7) * cpx + (blockIdx.x >> 3);
  int bx = swz % NBX, by = swz / NBX;
  int n0 = bx << 8, m0 = by << 8;

  int scol = ((lane & 7) ^ (lane >> 3)) << 3;
  size_t aOff = (size_t)((w << 4) + (lane >> 3)) * Kdim + scol;
  u16* ldsU = lds;

  auto stageA = [&](int buf, int h, int t) {
    const u16* g = A + (size_t)(m0 + (h << 7)) * Kdim + ((size_t)t << 6) + aOff;
    u16* l = ldsU + buf * 32768 + h * 8192 + (w << 10);
    gload16(g, l);
    gload16(g + ((size_t)Kdim << 3), l + 512);
  };
  auto stageB = [&](int buf, int h, int t) {
    const u16* g = Bt + (size_t)(n0 + (h << 7)) * Kdim + ((size_t)t << 6) + aOff;
    u16* l = ldsU + buf * 32768 + 16384 + h * 8192 + (w << 10);
    gload16(g, l);
    gload16(g + ((size_t)Kdim << 3), l + 512);
  };

  const u16* lA0p = ldsU;
  const u16* lB0p = ldsU + 16384;
  const u16* lA1p = ldsU + 32768;
  const u16* lB1p = ldsU + 49152;
  int arow = (wm * 128 + lr) * 64;
  int brow = (wn * 64 + lr) * 64;
  int swz0 = (((lg * 16)) ^ ((lr & 7) << 4)) >> 1;
  int swz1 = ((64 + lg * 16) ^ ((lr & 7) << 4)) >> 1;

  f32x4 acc[8][4] = {};
  bf16x8 ar[2][4], br[2][4];

#define READ_A_KS(BASE, MSEG, KS)                                            \
  do {                                                                       \
    _Pragma("unroll") for (int mm = 0; mm < 4; ++mm) {                       \
      const u16* p_ = (BASE) + arow + ((MSEG) * 64 + mm * 16) * 64;          \
      ar[KS][mm] = *(const bf16x8*)(p_ + ((KS) ? swz1 : swz0));              \
    }                                                                        \
  } while (0)
#define READ_B_KS(BASE, NSEG, KS)                                            \
  do {                                                                       \
    _Pragma("unroll") for (int nn = 0; nn < 2; ++nn) {                       \
      const u16* p_ = (BASE) + brow + ((NSEG) * 32 + nn * 16) * 64;          \
      br[KS][(NSEG) * 2 + nn] = *(const bf16x8*)(p_ + ((KS) ? swz1 : swz0)); \
    }                                                                        \
  } while (0)
#define MFMA_Q(MSEG, NSEG)                                                   \
  do {                                                                       \
    __builtin_amdgcn_s_setprio(1);                                           \
    _Pragma("unroll") for (int ks = 0; ks < 2; ++ks)                         \
      _Pragma("unroll") for (int mm = 0; mm < 4; ++mm)                       \
        _Pragma("unroll") for (int nn = 0; nn < 2; ++nn)                     \
          acc[(MSEG) * 4 + mm][(NSEG) * 2 + nn] =                            \
              __builtin_amdgcn_mfma_f32_16x16x32_bf16(                       \
                  ar[ks][mm], br[ks][(NSEG) * 2 + nn],                       \
                  acc[(MSEG) * 4 + mm][(NSEG) * 2 + nn], 0, 0, 0);           \
    __builtin_amdgcn_s_setprio(0);                                           \
  } while (0)
#define PSYNC()                                                              \
  do {                                                                       \
    __builtin_amdgcn_sched_barrier(0);                                       \
    asm volatile("s_waitcnt lgkmcnt(0)" ::: "memory");                       \
    __builtin_amdgcn_s_barrier();                                            \
    __builtin_amdgcn_sched_barrier(0);                                       \
  } while (0)
#define PSYNC_V(N)                                                           \
  do {                                                                       \
    __builtin_amdgcn_sched_barrier(0);                                       \
    asm volatile("s_waitcnt vmcnt(" #N ") lgkmcnt(0)" ::: "memory");         \
    __builtin_amdgcn_s_barrier();                                            \
    __builtin_amdgcn_sched_barrier(0);                                       \
  } while (0)

  int NK = Kdim >> 6, NI = NK >> 1;
  // prologue: tile0 -> buf0 (A+B), tile1 B -> buf1
  stageA(0, 0, 0); stageA(0, 1, 0); stageB(0, 0, 0); stageB(0, 1, 0);
  stageB(1, 0, 1); stageB(1, 1, 1);
  asm volatile("s_waitcnt vmcnt(4)" ::: "memory");
  __builtin_amdgcn_s_barrier();
  __builtin_amdgcn_sched_barrier(0);

  for (int i = 0; i < NI; ++i) {
    int t1 = 2 * i + 1, t2 = 2 * i + 2, t3 = 2 * i + 3;
    bool last = (i == NI - 1);
    // ---- P1 ----
    stageA(1, 0, t1); stageA(1, 1, t1);
    READ_A_KS(lA0p, 0, 0); READ_B_KS(lB0p, 0, 0); READ_B_KS(lB0p, 1, 0);
    READ_A_KS(lA0p, 0, 1); READ_B_KS(lB0p, 0, 1); READ_B_KS(lB0p, 1, 1);
    MFMA_Q(0, 0); MFMA_Q(0, 1);
    PSYNC();
    // ---- P2 ----
    if (!last) { stageB(0, 0, t2); stageB(0, 1, t2); }
    READ_A_KS(lA0p, 1, 0); READ_A_KS(lA0p, 1, 1);
    MFMA_Q(1, 0); MFMA_Q(1, 1);
    if (last) PSYNC_V(0);
    else      PSYNC_V(4);
    // ---- P3 ----
    if (!last) { stageA(0, 0, t2); stageA(0, 1, t2); }
    READ_A_KS(lA1p, 0, 0); READ_B_KS(lB1p, 0, 0); READ_B_KS(lB1p, 1, 0);
    READ_A_KS(lA1p, 0, 1); READ_B_KS(lB1p, 0, 1); READ_B_KS(lB1p, 1, 1);
    MFMA_Q(0, 0); MFMA_Q(0, 1);
    PSYNC();
    // ---- P4 ----
    if (!last) { stageB(1, 0, t3); stageB(1, 1, t3); }
    READ_A_KS(lA1p, 1, 0); READ_A_KS(lA1p, 1, 1);
    MFMA_Q(1, 0); MFMA_Q(1, 1);
    if (last) PSYNC();
    else      PSYNC_V(4);
  }

  // ---- epilogue ----
#pragma unroll
  for (int m = 0; m < 8; ++m) {
#pragma unroll
    for (int n = 0; n < 4; ++n) {
      int col = n0 + wn * 64 + n * 16 + lr;
      float bv = BIAS ? bias[col] : 0.0f;
#pragma unroll
      for (int r = 0; r < 4; ++r) {
        int row = m0 + wm * 128 + m * 16 + lg * 4 + r;
        float v = acc[m][n][r];
        if (BIAS) v += bv;
        if (GELU_) v = fast_gelu(v);
        if (RESID) v += bf2f(resid[(size_t)row * N + col]);
        Cout[(size_t)row * N + col] = f2bf(v);
      }
    }
  }
#undef READ_A_KS
#undef READ_B_KS
#undef MFMA_Q
#undef PSYNC
#undef PSYNC_V
}

// --------- per-batch sim precompute: psim[b] = (norm(s_b)*SBOOST2)(...)^T ---------
__global__ __launch_bounds__(256) void simpre_kernel(
    const u16* __restrict__ qkvb, u16* __restrict__ psim) {
  __shared__ u16 sln[128][200];
  int b = blockIdx.x, tid = threadIdx.x;
  {
    int row = tid >> 1, half = tid & 1;
    const u16* sr = qkvb + ((size_t)(b * K + row)) * QKVW + SIMOFF + half * 96;
    u16 v[96];
    float sq = 0.f;
#pragma unroll
    for (int j = 0; j < 12; ++j) {
      uint4 u4 = *(const uint4*)(sr + j * 8);
      u32 uu[4] = {u4.x, u4.y, u4.z, u4.w};
#pragma unroll
      for (int t = 0; t < 4; ++t) {
        v[j * 8 + 2 * t] = (u16)(uu[t] & 0xffffu);
        v[j * 8 + 2 * t + 1] = (u16)(uu[t] >> 16);
      }
    }
#pragma unroll
    for (int j = 0; j < 96; ++j) { float f = bf2f(v[j]); sq += f * f; }
    sq += __shfl_xor(sq, 1, 64);
    float inv = SBOOST2 / fmaxf(sqrtf(sq), 1e-12f);
#pragma unroll
    for (int j = 0; j < 96; ++j) sln[row][half * 96 + j] = f2bf(bf2f(v[j]) * inv);
  }
  __syncthreads();
  int w = tid >> 6, lane = tid & 63;
  int lr = lane & 15, lg = lane >> 4;
  int q0 = 32 * w;
  f32x4 accs[2][8] = {};
#pragma unroll
  for (int ks = 0; ks < 6; ++ks) {
    bf16x8 af[2];
#pragma unroll
    for (int m = 0; m < 2; ++m)
      af[m] = *(const bf16x8*)(&sln[q0 + 16 * m + lr][ks * 32 + lg * 8]);
#pragma unroll
    for (int n = 0; n < 8; ++n) {
      bf16x8 bf = *(const bf16x8*)(&sln[16 * n + lr][ks * 32 + lg * 8]);
#pragma unroll
      for (int m = 0; m < 2; ++m)
        accs[m][n] = __builtin_amdgcn_mfma_f32_16x16x32_bf16(af[m], bf, accs[m][n], 0, 0, 0);
    }
  }
  u16* pb = psim + (size_t)b * K * K;
#pragma unroll
  for (int m = 0; m < 2; ++m)
#pragma unroll
    for (int n = 0; n < 8; ++n)
#pragma unroll
      for (int r = 0; r < 4; ++r)
        pb[(size_t)(q0 + 16 * m + 4 * lg + r) * K + 16 * n + lr] = f2bf(accs[m][n][r]);
}

// ---------------- MFMA attention (verified r14): K staged into Pl region ----------------
__global__ __launch_bounds__(256) void attn_kernel(
    const u16* __restrict__ qkv, const u16* __restrict__ psim,
    u16* __restrict__ ob) {
  __shared__ u16 Vt[96][136];
  __shared__ u16 Pl[4][32][136];  // holds K [128][104] until P overwrites it
  int bh = blockIdx.x, b = bh >> 3, h = bh & 7;
  int tid = threadIdx.x, w = tid >> 6, lane = tid & 63;
  int lr = lane & 15, lg = lane >> 4;
  const u16* qb = qkv + (size_t)b * K * QKVW + h * HD;
  const u16* kb = qb + D;
  const u16* vb = qb + 2 * D;
  // stage V transposed
  for (int idx = tid; idx < 128 * 12; idx += 256) {
    int r = idx / 12, db = idx - r * 12;
    uint4 v4 = *(const uint4*)(vb + (size_t)r * QKVW + db * 8);
    u32 vv[4] = {v4.x, v4.y, v4.z, v4.w};
#pragma unroll
    for (int j = 0; j < 4; ++j) {
      Vt[db * 8 + 2 * j][r] = (u16)(vv[j] & 0xffffu);
      Vt[db * 8 + 2 * j + 1][r] = (u16)(vv[j] >> 16);
    }
  }
  // stage K row-major into Pl region as [128][104]
  u16* Kl = &Pl[0][0][0];
  for (int idx = tid; idx < 128 * 12; idx += 256) {
    int r = idx / 12, db = idx - r * 12;
    *(uint4*)(Kl + r * 104 + db * 8) = *(const uint4*)(kb + (size_t)r * QKVW + db * 8);
  }
  __syncthreads();
  int q0 = 32 * w;
  f32x4 accs[2][8] = {};
#pragma unroll
  for (int ks = 0; ks < 3; ++ks) {
    bf16x8 af[2];
#pragma unroll
    for (int m = 0; m < 2; ++m)
      af[m] = *(const bf16x8*)(qb + (size_t)(q0 + 16 * m + lr) * QKVW + ks * 32 + lg * 8);
#pragma unroll
    for (int n = 0; n < 8; ++n) {
      bf16x8 bf = *(const bf16x8*)(Kl + (16 * n + lr) * 104 + ks * 32 + lg * 8);
#pragma unroll
      for (int m = 0; m < 2; ++m)
        accs[m][n] = __builtin_amdgcn_mfma_f32_16x16x32_bf16(af[m], bf, accs[m][n], 0, 0, 0);
    }
  }
  __syncthreads();  // all waves' K reads complete before P overwrites the region
  const u16* pb = psim + (size_t)b * K * K;
#pragma unroll
  for (int m = 0; m < 2; ++m)
#pragma unroll
    for (int n = 0; n < 8; ++n)
#pragma unroll
      for (int r = 0; r < 4; ++r)
        accs[m][n][r] += bf2f(pb[(size_t)(q0 + 16 * m + 4 * lg + r) * 128 + 16 * n + lr]);
  // softmax (exp2 domain) + write P
#pragma unroll
  for (int m = 0; m < 2; ++m) {
    float mx[4] = {-3e38f, -3e38f, -3e38f, -3e38f};
#pragma unroll
    for (int n = 0; n < 8; ++n)
#pragma unroll
      for (int r = 0; r < 4; ++r) mx[r] = fmaxf(mx[r], accs[m][n][r]);
#pragma unroll
    for (int r = 0; r < 4; ++r) {
      mx[r] = fmaxf(mx[r], __shfl_xor(mx[r], 1, 64));
      mx[r] = fmaxf(mx[r], __shfl_xor(mx[r], 2, 64));
      mx[r] = fmaxf(mx[r], __shfl_xor(mx[r], 4, 64));
      mx[r] = fmaxf(mx[r], __shfl_xor(mx[r], 8, 64));
    }
    float sm[4] = {0.f, 0.f, 0.f, 0.f};
#pragma unroll
    for (int n = 0; n < 8; ++n)
#pragma unroll
      for (int r = 0; r < 4; ++r) {
        float e = __builtin_amdgcn_exp2f(accs[m][n][r] - mx[r]);
        accs[m][n][r] = e;
        sm[r] += e;
      }
#pragma unroll
    for (int r = 0; r < 4; ++r) {
      sm[r] += __shfl_xor(sm[r], 1, 64);
      sm[r] += __shfl_xor(sm[r], 2, 64);
      sm[r] += __shfl_xor(sm[r], 4, 64);
      sm[r] += __shfl_xor(sm[r], 8, 64);
    }
    float inv[4];
#pragma unroll
    for (int r = 0; r < 4; ++r) inv[r] = 1.0f / sm[r];
#pragma unroll
    for (int n = 0; n < 8; ++n)
#pragma unroll
      for (int r = 0; r < 4; ++r)
        Pl[w][16 * m + 4 * lg + r][16 * n + lr] = f2bf(accs[m][n][r] * inv[r]);
  }
  __syncthreads();
  // PV
  f32x4 acco[2][6] = {};
#pragma unroll
  for (int ks = 0; ks < 4; ++ks) {
    bf16x8 pa[2];
#pragma unroll
    for (int m = 0; m < 2; ++m)
      pa[m] = *(const bf16x8*)(&Pl[w][16 * m + lr][ks * 32 + lg * 8]);
#pragma unroll
    for (int n = 0; n < 6; ++n) {
      bf16x8 bv = *(const bf16x8*)(&Vt[16 * n + lr][ks * 32 + lg * 8]);
#pragma unroll
      for (int m = 0; m < 2; ++m)
        acco[m][n] = __builtin_amdgcn_mfma_f32_16x16x32_bf16(pa[m], bv, acco[m][n], 0, 0, 0);
    }
  }
  u16* obb = ob + (size_t)b * K * D + h * HD;
#pragma unroll
  for (int m = 0; m < 2; ++m)
#pragma unroll
    for (int n = 0; n < 6; ++n)
#pragma unroll
      for (int r = 0; r < 4; ++r)
        obb[(size_t)(q0 + 16 * m + 4 * lg + r) * D + 16 * n + lr] = f2bf(acco[m][n][r]);
}

// ---------------- host ----------------
extern "C" void kernel_launch(void* const* d_in, const int* in_sizes, int n_in,
                              void* d_out, int out_size, void* d_ws, size_t ws_size,
                              hipStream_t stream) {
  (void)in_sizes; (void)n_in; (void)out_size;
  const float* slots = (const float*)d_in[0];
  const float* pos   = (const float*)d_in[1];
  const float* Wq    = (const float*)d_in[2];
  const float* Wk    = (const float*)d_in[3];
  const float* Wv    = (const float*)d_in[4];
  const float* Wo    = (const float*)d_in[5];
  const float* bo    = (const float*)d_in[6];
  const float* Wsim  = (const float*)d_in[7];
  const float* g1    = (const float*)d_in[8];
  const float* b1    = (const float*)d_in[9];
  const float* g2    = (const float*)d_in[10];
  const float* b2    = (const float*)d_in[11];
  const float* Wff1  = (const float*)d_in[12];
  const float* bff1  = (const float*)d_in[13];
  const float* Wff2  = (const float*)d_in[14];
  const float* bff2  = (const float*)d_in[15];
  const float* gf    = (const float*)d_in[16];
  const float* bfin  = (const float*)d_in[17];

  char* p = (char*)d_ws;
  u16*   x    = (u16*)p;   p += (size_t)M * D * 2;          // 25.2 MB
  u16*   nx   = (u16*)p;   p += (size_t)M * D * 2;          // 25.2 MB
  u16*   qkvb = (u16*)p;   p += (size_t)M * QKVW * 2;       // 83.9 MB
  u16*   ob   = (u16*)p;   p += (size_t)M * D * 2;          // 25.2 MB
  u16*   psim = (u16*)p;   p += (size_t)B * K * K * 2;      // 4.2 MB
  u16*   wtA4 = (u16*)p;   p += (size_t)4 * QKVW * D * 2;   // 15.7 MB
  u16*   wtB4 = (u16*)p;   p += (size_t)4 * D * D * 2;      // 4.7 MB
  u16*   wtC4 = (u16*)p;   p += (size_t)4 * FFD * D * 2;    // 18.9 MB
  u16*   wtD4 = (u16*)p;   p += (size_t)4 * D * FFD * 2;    // 18.9 MB
  if ((size_t)(p - (char*)d_ws) > ws_size) return;          // 221.8 MB <= proven 222.3
  u16* hb = qkvb;  // [M][3072] ffn hidden (spans qkvb+ob = 109 MB >= 100.7 MB)

  WAll wp = {Wq, Wk, Wv, Wo, Wsim, Wff1, Wff2, wtA4, wtB4, wtC4, wtD4,
             slots, pos, x};
  wconv_all_kernel<<<28224 + 6144, 256, 0, stream>>>(wp, QSCALE);

  int nbx_qkv = QKVW / 256, nwg_qkv = nbx_qkv * (M / 256);  // 10 x 64 = 640
  int nbx_o   = D / 256,    nwg_o   = nbx_o * (M / 256);    // 3 x 64 = 192
  int nbx_f1  = FFD / 256,  nwg_f1  = nbx_f1 * (M / 256);   // 12 x 64 = 768

  for (int l = 0; l < NL; ++l) {
    ln_kernel<true><<<M / 4, 256, 0, stream>>>(x, g1 + l * D, b1 + l * D, nx);
    gemm256_kernel<false, false, false><<<nwg_qkv, 512, 0, stream>>>(
        nx, wtA4 + (size_t)l * QKVW * D, nullptr, nullptr, qkvb, QKVW, D, nbx_qkv);
    simpre_kernel<<<B, 256, 0, stream>>>(qkvb, psim);
    attn_kernel<<<B * NH, 256, 0, stream>>>(qkvb, psim, ob);
    gemm256_kernel<true, false, true><<<nwg_o, 512, 0, stream>>>(
        ob, wtB4 + (size_t)l * D * D, bo + l * D, x, x, D, D, nbx_o);
    ln_kernel<true><<<M / 4, 256, 0, stream>>>(x, g2 + l * D, b2 + l * D, nx);
    gemm256_kernel<true, true, false><<<nwg_f1, 512, 0, stream>>>(
        nx, wtC4 + (size_t)l * FFD * D, bff1 + l * FFD, nullptr, hb, FFD, D, nbx_f1);
    gemm256_kernel<true, false, true><<<nwg_o, 512, 0, stream>>>(
        hb, wtD4 + (size_t)l * D * FFD, bff2 + l * D, x, x, D, FFD, nbx_o);
  }
  ln_kernel<false><<<M / 4, 256, 0, stream>>>(x, gf, bfin, d_out);
}